// Round 14
// baseline (231.190 us; speedup 1.0000x reference)
//
#include <hip/hip_runtime.h>
#include <math.h>

#define DIMM 256
#define HEADS 8
#define NB 2048
#define BB 2
#define ROWS (BB*NB)   // 4096

typedef __attribute__((ext_vector_type(8))) short bf16x8;
typedef __attribute__((ext_vector_type(4))) short bf16x4;
typedef __attribute__((ext_vector_type(4))) float f32x4;

__device__ inline unsigned short f2bf(float f) {
    unsigned int u = __float_as_uint(f);
    u += 0x7FFFu + ((u >> 16) & 1u);           // RNE
    return (unsigned short)(u >> 16);
}
__device__ inline float bf2f(unsigned short u) {
    return __uint_as_float(((unsigned int)u) << 16);
}

__device__ inline int get_mask(const void* nm, int fmt, int idx) {
    if (fmt) return ((const unsigned char*)nm)[idx] != 0;
    return ((const int*)nm)[idx] != 0;
}

// ---------------- scan (blocks 0..BB-1) + w2bfT (blocks BB..BB+191) ------------------
__global__ __launch_bounds__(256) void scan_w2bft_kernel(
    const void* __restrict__ nmask, int* __restrict__ nv,
    unsigned short* __restrict__ qidx,
    const float* __restrict__ w0, const float* __restrict__ w1,
    const float* __restrict__ w2, const float* __restrict__ w3,
    unsigned short* __restrict__ o0, unsigned short* __restrict__ o1,
    unsigned short* __restrict__ o2, unsigned short* __restrict__ o3)
{
    __shared__ float tile[64][65];
    __shared__ int fsh;
    __shared__ int cnt[256];
    __shared__ int base[256];
    int bid = blockIdx.x, t = threadIdx.x;
    if (bid < BB) {
        if (t == 0) fsh = 0;
        __syncthreads();
        if (((const unsigned char*)nmask)[4 * t + 1] != 0) fsh = 1;
        __syncthreads();
        int fm = fsh;
        int b = bid;
        int m[8]; int c = 0;
#pragma unroll
        for (int i = 0; i < 8; ++i) {
            m[i] = get_mask(nmask, fm, b * NB + t * 8 + i);
            c += m[i];
        }
        cnt[t] = c;
        __syncthreads();
        if (t == 0) {
            int acc = 0;
            for (int i = 0; i < 256; ++i) { base[i] = acc; acc += cnt[i]; }
            nv[b] = acc;
        }
        __syncthreads();
        int off = base[t];
#pragma unroll
        for (int i = 0; i < 8; ++i) {
            int row = t * 8 + i;
            if (m[i]) qidx[b * NB + off++] = (unsigned short)row;
        }
        __syncthreads();
        if (t == 0) {   // pad to multiple of 64 with last valid row (safe dup reads)
            int n = nv[b];
            unsigned short last = (n > 0) ? qidx[b * NB + n - 1] : (unsigned short)0;
            int padend = (n + 63) & ~63;
            for (int i = n; i < padend; ++i) qidx[b * NB + i] = last;
        }
    } else {
        int wb = bid - BB;
        const float* src; unsigned short* dst; int K, N, idx;
        if (wb < 48)       { src = w0; dst = o0; K = 256;  N = 768;  idx = wb; }
        else if (wb < 64)  { src = w1; dst = o1; K = 256;  N = 256;  idx = wb - 48; }
        else if (wb < 128) { src = w2; dst = o2; K = 256;  N = 1024; idx = wb - 64; }
        else               { src = w3; dst = o3; K = 1024; N = 256;  idx = wb - 128; }
        int ntiles = N >> 6;
        int k0 = (idx / ntiles) * 64, n0 = (idx % ntiles) * 64;
        int r = t >> 4, c4 = (t & 15) * 4;
#pragma unroll
        for (int i = 0; i < 4; ++i) {
            float4 v = *(const float4*)&src[(size_t)(k0 + r + i * 16) * N + n0 + c4];
            tile[r + i * 16][c4 + 0] = v.x;
            tile[r + i * 16][c4 + 1] = v.y;
            tile[r + i * 16][c4 + 2] = v.z;
            tile[r + i * 16][c4 + 3] = v.w;
        }
        __syncthreads();
#pragma unroll
        for (int i = 0; i < 4; ++i) {
            int n = n0 + r + i * 16;
            ushort4 u;
            u.x = f2bf(tile[c4 + 0][r + i * 16]);
            u.y = f2bf(tile[c4 + 1][r + i * 16]);
            u.z = f2bf(tile[c4 + 2][r + i * 16]);
            u.w = f2bf(tile[c4 + 3][r + i * 16]);
            *(ushort4*)&dst[(size_t)n * K + k0 + c4] = u;
        }
    }
}

// ---------------- LayerNorm body: read row xrow, write compact slot orow ----------
__device__ inline void ln8_body(const float* __restrict__ x, const float* __restrict__ g,
                                const float* __restrict__ bb, unsigned short* __restrict__ o,
                                int xrow, int orow, int lane32) {
    int c0 = lane32 * 8;
    float4 v0 = *(const float4*)&x[(size_t)xrow * DIMM + c0];
    float4 v1 = *(const float4*)&x[(size_t)xrow * DIMM + c0 + 4];
    float s  = v0.x + v0.y + v0.z + v0.w + v1.x + v1.y + v1.z + v1.w;
    float s2 = v0.x*v0.x + v0.y*v0.y + v0.z*v0.z + v0.w*v0.w
             + v1.x*v1.x + v1.y*v1.y + v1.z*v1.z + v1.w*v1.w;
#pragma unroll
    for (int off = 16; off >= 1; off >>= 1) {
        s  += __shfl_xor(s,  off);
        s2 += __shfl_xor(s2, off);
    }
    float mean = s * (1.0f / DIMM);
    float var  = s2 * (1.0f / DIMM) - mean * mean;
    float rstd = rsqrtf(var + 1e-5f);
    float4 g0 = *(const float4*)&g[c0],  g1 = *(const float4*)&g[c0 + 4];
    float4 b0 = *(const float4*)&bb[c0], b1 = *(const float4*)&bb[c0 + 4];
    ushort4 u0, u1;
    u0.x = f2bf((v0.x - mean) * rstd * g0.x + b0.x);
    u0.y = f2bf((v0.y - mean) * rstd * g0.y + b0.y);
    u0.z = f2bf((v0.z - mean) * rstd * g0.z + b0.z);
    u0.w = f2bf((v0.w - mean) * rstd * g0.w + b0.w);
    u1.x = f2bf((v1.x - mean) * rstd * g1.x + b1.x);
    u1.y = f2bf((v1.y - mean) * rstd * g1.y + b1.y);
    u1.z = f2bf((v1.z - mean) * rstd * g1.z + b1.z);
    u1.w = f2bf((v1.w - mean) * rstd * g1.w + b1.w);
    *(ushort4*)&o[(size_t)orow * DIMM + c0]     = u0;
    *(ushort4*)&o[(size_t)orow * DIMM + c0 + 4] = u1;
}

// ---------------- prep: compact LN1 (0..511) + emaskP (512..2559) --------------------
// emaskP (fully compact): per (b, qt16, kt) unit of 512B. Lane L holds int2 at L*8:
// nibble for [q slot = qt16*16 + (L&15)][key slot = kt*64 + t16*16 + (L>>4)*4 + r]
// in dword (t16>>1), bits ((t16&1)*16 + r*4). Code 0 = invalid; else etype+1.
__global__ __launch_bounds__(256) void prep_kernel(
    const float* __restrict__ x, const float* __restrict__ ln1_g,
    const float* __restrict__ ln1_b, unsigned short* __restrict__ h_ln,
    const int* __restrict__ etypes,
    unsigned char* __restrict__ emaskP,
    const int* __restrict__ nv, const unsigned short* __restrict__ qidx)
{
    int bid = blockIdx.x, t = threadIdx.x;
    if (bid < 512) {
        int slotg = bid * 8 + (t >> 5);
        int b = slotg >> 11, sl = slotg & 2047;
        int nvp = (nv[b] + 63) & ~63;
        if (sl < nvp) {
            int row = qidx[b * NB + sl];
            ln8_body(x, ln1_g, ln1_b, h_ln, b * NB + row, slotg, t & 31);
        }
    } else {
        int unit = (bid - 512) * 4 + (t >> 6);
        int lane = t & 63, quad = lane >> 4, l15 = lane & 15;
        int b = unit >> 12;                 // 4096 units per batch
        int qt16 = (unit >> 5) & 127;
        int kt = unit & 31;
        int nvb = nv[b];
        int nvp = (nvb + 63) & ~63;
        if (qt16 * 16 >= nvb || kt * 64 >= nvp) return;
        int slot = qt16 * 16 + l15;
        int validq = slot < nvb;
        int qr = qidx[b * NB + slot];       // padded to mult-64, safe
        const int* erow = etypes + (size_t)(b * NB + qr) * NB;
        unsigned int dw[2] = {0u, 0u};
#pragma unroll
        for (int t16 = 0; t16 < 4; ++t16) {
#pragma unroll
            for (int r = 0; r < 4; ++r) {
                int ks = kt * 64 + t16 * 16 + quad * 4 + r;
                unsigned int code = 0u;
                if (validq && ks < nvb) {
                    int korig = qidx[b * NB + ks];
                    int et = erow[korig];
                    if ((et != 0) || (korig == qr)) code = (unsigned int)(et + 1);
                }
                dw[t16 >> 1] |= code << ((t16 & 1) * 16 + r * 4);
            }
        }
        int2 o = {(int)dw[0], (int)dw[1]};
        *(int2*)(emaskP + (size_t)unit * 512 + lane * 8) = o;
    }
}

// ---------------- compact qkv GEMM (64x64); q pre-scaled; per-batch grid -------------
__global__ __launch_bounds__(256) void gemm_qkv_mfma(
    const unsigned short* __restrict__ A, const unsigned short* __restrict__ Bt,
    const float* __restrict__ bias, const int* __restrict__ nv,
    unsigned short* __restrict__ qkvh, unsigned short* __restrict__ vT)
{
    const int K = 256;
    int t = threadIdx.x, w = t >> 6, l = t & 63;
    int l15 = l & 15, quad = l >> 4;
    int n0 = blockIdx.x * 64;
    int m0c = blockIdx.y * 64;
    int b = blockIdx.z;
    int nvp = (nv[b] + 63) & ~63;
    if (m0c >= nvp) return;
    const unsigned short* ap = A + (size_t)(b * NB + m0c + w * 16 + l15) * K + quad * 8;
    const unsigned short* bp = Bt + (size_t)(n0 + l15) * K + quad * 8;

    f32x4 acc[4];
#pragma unroll
    for (int c = 0; c < 4; ++c) acc[c] = (f32x4){0.f, 0.f, 0.f, 0.f};

    bf16x8 aA, bA[4], aB, bB[4];
    auto ld = [&](bf16x8& af, bf16x8 (&bf)[4], int k0) {
        af = *(const bf16x8*)(ap + k0);
#pragma unroll
        for (int c = 0; c < 4; ++c)
            bf[c] = *(const bf16x8*)(bp + (size_t)(c * 16) * K + k0);
    };
    auto pr = [&](const bf16x8& af, const bf16x8 (&bf)[4]) {
#pragma unroll
        for (int c = 0; c < 4; ++c)
            acc[c] = __builtin_amdgcn_mfma_f32_16x16x32_bf16(af, bf[c], acc[c], 0, 0, 0);
    };
    ld(aA, bA, 0);
    for (int k0 = 0; k0 < K; k0 += 64) {
        ld(aB, bB, k0 + 32);
        pr(aA, bA);
        if (k0 + 64 < K) ld(aA, bA, k0 + 64);
        pr(aB, bB);
    }

    if (n0 < 512) {
        float sc = (n0 < 256) ? 0.17677669529663689f : 1.0f;   // fold 1/sqrt(32) into q
#pragma unroll
        for (int r = 0; r < 4; ++r) {
            int slot = b * NB + m0c + w * 16 + quad * 4 + r;
#pragma unroll
            for (int c = 0; c < 4; ++c) {
                int col = n0 + c * 16 + l15;
                qkvh[(size_t)slot * 512 + col] = f2bf((acc[c][r] + bias[col]) * sc);
            }
        }
    } else {
        int n = m0c + w * 16 + quad * 4;
#pragma unroll
        for (int c = 0; c < 4; ++c) {
            int col = n0 + c * 16 + l15 - 512;
            int hidx = col >> 5, d = col & 31;
            float bs = bias[n0 + c * 16 + l15];
            ushort4 u;
            u.x = f2bf(acc[c][0] + bs);
            u.y = f2bf(acc[c][1] + bs);
            u.z = f2bf(acc[c][2] + bs);
            u.w = f2bf(acc[c][3] + bs);
            *(ushort4*)&vT[(size_t)((b * HEADS + hidx) * 32 + d) * NB + n] = u;
        }
    }
}

// ---------------- MFMA attention: fully compact (q AND k), S^T + b64 P + R6 PV -------
__global__ __launch_bounds__(256) void attn_mfma(
    const unsigned short* __restrict__ qkvh,  // compact [4096][512] bf16: q(scaled)|k
    const unsigned short* __restrict__ vT,    // compact [512][2048] bf16
    const unsigned char* __restrict__ emaskP, // 4-bit fully-compact codes
    const float* __restrict__ table,
    const int* __restrict__ nv,
    unsigned short* __restrict__ OpH, float* __restrict__ lpart)
{
    __shared__ unsigned short P[4][16][72];
    __shared__ float tab2m[16];

    int t = threadIdx.x;
    int w = t >> 6, l = t & 63;
    int l15 = l & 15, quad = l >> 4;
    int h = blockIdx.x;                       // fastest -> id%8 == h (XCD pin)
    int qt = blockIdx.y;
    int z = blockIdx.z, b = z >> 2, sp = z & 3;

    if (t < 16) tab2m[t] = (t >= 1 && t < 10) ? __expf(table[(t - 1) * 8 + h]) : 0.f;
    __syncthreads();                          // no barriers after this point

    int nvb = nv[b];
    int qt16 = qt * 4 + w;
    int q0c = qt16 * 16;
    if (q0c >= nvb) return;                   // compact-q skip

    int nkt = (nvb + 63) >> 6;                // key tiles
    int tps = (nkt + 3) >> 2;                 // tiles per split
    int kbase = sp * tps * 64;
    int kend = min(kbase + tps * 64, nkt * 64);

    bf16x8 bq = *(const bf16x8*)(qkvh + (size_t)(b * NB + q0c + l15) * 512 + h * 32 + quad * 8);

    const unsigned short* kp = qkvh + (size_t)(b * NB + l15) * 512 + 256 + h * 32 + quad * 8;
    const unsigned short* vp = vT + (size_t)((b * HEADS + h) * 32 + l15) * NB + quad * 8;
    const unsigned char* ep = emaskP + (size_t)((b * 128 + qt16) * 32) * 512 + l * 8;

    float lacc = 0.f;
    f32x4 O0 = {0.f, 0.f, 0.f, 0.f}, O1 = {0.f, 0.f, 0.f, 0.f};

    bf16x8 kA[4], kB[4];
    bf16x8 vA[2][2], vB[2][2];
    int2 eA, eB;

    auto loadtile = [&](bf16x8 (&kf)[4], bf16x8 (&vf)[2][2], int2& ef, int m0) {
#pragma unroll
        for (int t16 = 0; t16 < 4; ++t16)
            kf[t16] = *(const bf16x8*)(kp + (size_t)(m0 + t16 * 16) * 512);
#pragma unroll
        for (int ks = 0; ks < 2; ++ks) {
            vf[ks][0] = *(const bf16x8*)(vp + m0 + ks * 32);
            vf[ks][1] = *(const bf16x8*)(vp + 16 * NB + m0 + ks * 32);
        }
        ef = *(const int2*)(ep + (size_t)(m0 >> 6) * 512);
    };

    auto process = [&](const bf16x8 (&kf)[4], const bf16x8 (&vf)[2][2], const int2& ef) {
#pragma unroll
        for (int t16 = 0; t16 < 4; ++t16) {
            f32x4 zero = {0.f, 0.f, 0.f, 0.f};
            f32x4 sT = __builtin_amdgcn_mfma_f32_16x16x32_bf16(kf[t16], bq, zero, 0, 0, 0);
            unsigned int e = ((unsigned int)((t16 < 2) ? ef.x : ef.y)) >> ((t16 & 1) * 16);
            float p0 = __expf(sT[0]) * tab2m[e & 0xFu];
            float p1 = __expf(sT[1]) * tab2m[(e >> 4) & 0xFu];
            float p2 = __expf(sT[2]) * tab2m[(e >> 8) & 0xFu];
            float p3 = __expf(sT[3]) * tab2m[(e >> 12) & 0xFu];
            lacc += (p0 + p1) + (p2 + p3);
            bf16x4 pb;
            pb[0] = (short)f2bf(p0); pb[1] = (short)f2bf(p1);
            pb[2] = (short)f2bf(p2); pb[3] = (short)f2bf(p3);
            *(bf16x4*)&P[w][l15][t16 * 16 + quad * 4] = pb;
        }
#pragma unroll
        for (int ks = 0; ks < 2; ++ks) {
            bf16x8 pa = *(const bf16x8*)&P[w][l15][ks * 32 + quad * 8];
            O0 = __builtin_amdgcn_mfma_f32_16x16x32_bf16(pa, vf[ks][0], O0, 0, 0, 0);
            O1 = __builtin_amdgcn_mfma_f32_16x16x32_bf16(pa, vf[ks][1], O1, 0, 0, 0);
        }
    };

    if (kbase < kend) {
        loadtile(kA, vA, eA, kbase);
        for (int m0 = kbase; m0 < kend; m0 += 128) {
            int n1 = (m0 + 64 < kend) ? m0 + 64 : kbase;
            loadtile(kB, vB, eB, n1);
            process(kA, vA, eA);
            if (m0 + 128 < kend) loadtile(kA, vA, eA, m0 + 128);
            if (m0 + 64 < kend) process(kB, vB, eB);
        }
    }

    lacc += __shfl_xor(lacc, 16);
    lacc += __shfl_xor(lacc, 32);

    unsigned short* Ob = OpH + (size_t)sp * ROWS * DIMM;
#pragma unroll
    for (int r = 0; r < 4; ++r) {
        int slot = q0c + quad * 4 + r;
        if (slot < nvb) {
            Ob[(size_t)(b * NB + slot) * DIMM + h * 32 + l15]      = f2bf(O0[r]);
            Ob[(size_t)(b * NB + slot) * DIMM + h * 32 + 16 + l15] = f2bf(O1[r]);
        }
    }
    if (quad == 0 && q0c + l15 < nvb)
        lpart[(size_t)sp * ROWS * 8 + (size_t)(b * NB + q0c + l15) * 8 + h] = lacc;
}

// ---------------- megaback: 8 rows/block compute (0..511) + masked copy (512..639) ---
// Compute: active blocks = ceil(nv/8) per batch -> ~256 total (1/CU vs R13's 0.5/CU).
// A-rows duplicated via l15&7 (wasted MFMA rows free; phases are latency-bound).
__global__ __launch_bounds__(1024) void megaback(
    const unsigned short* __restrict__ OpH, const float* __restrict__ lpart,
    const unsigned short* __restrict__ projT, const float* __restrict__ proj_b,
    const float* __restrict__ x, const void* __restrict__ nmask,
    const float* __restrict__ g2, const float* __restrict__ b2,
    const unsigned short* __restrict__ f1T, const float* __restrict__ ffn_b1,
    const unsigned short* __restrict__ f2T, const float* __restrict__ ffn_b2,
    const int* __restrict__ nv, const unsigned short* __restrict__ qidx,
    float* __restrict__ out)
{
    __shared__ float rinv_l[8][8];
    __shared__ float stats[8][2];
    __shared__ float redn[8][16][2];
    __shared__ unsigned short Astage[8][264];
    __shared__ float x1s[8][260];
    __shared__ unsigned short hstage[8][264];
    __shared__ unsigned short midstage[8][1032];
    __shared__ int fsh;

    int t = threadIdx.x;
    int bid = blockIdx.x;

    if (bid >= 512) {
        // masked-row copy: out[row] = x[row] (proj*0, ffn*0 => exact)
        if (t == 0) fsh = 0;
        __syncthreads();
        if (((const unsigned char*)nmask)[4 * t + 1] != 0) fsh = 1;
        __syncthreads();
        int fm = fsh;
        int row = (bid - 512) * 32 + (t >> 5);
        if (!get_mask(nmask, fm, row)) {
            int c0 = (t & 31) * 8;
            float4 v0 = *(const float4*)&x[(size_t)row * DIMM + c0];
            float4 v1 = *(const float4*)&x[(size_t)row * DIMM + c0 + 4];
            *(float4*)&out[(size_t)row * DIMM + c0]     = v0;
            *(float4*)&out[(size_t)row * DIMM + c0 + 4] = v1;
        }
        return;
    }

    int w = t >> 6, l = t & 63;
    int l15 = l & 15, quad = l >> 4;
    int b = bid >> 8;
    int s0 = (bid & 255) * 8;
    int nvb = nv[b];
    if (s0 >= nvb) return;                    // block-uniform, before barriers
    int slot0 = b * NB + s0;

    if (t < 64) {
        int row = t >> 3, h = t & 7;
        float s = 0.f;
#pragma unroll
        for (int sp = 0; sp < 4; ++sp)
            s += lpart[(size_t)sp * ROWS * 8 + (size_t)(slot0 + row) * 8 + h];
        rinv_l[row][h] = (s > 0.f) ? 1.f / s : 0.f;
    }
    __syncthreads();

    if (t < 512) {
        int row = t >> 6, col4 = (t & 63) * 4;
        float rinv = rinv_l[row][col4 >> 5];
        float o0 = 0.f, o1 = 0.f, o2 = 0.f, o3 = 0.f;
#pragma unroll
        for (int sp = 0; sp < 4; ++sp) {
            ushort4 u = *(const ushort4*)&OpH[(size_t)sp * ROWS * DIMM +
                                             (size_t)(slot0 + row) * DIMM + col4];
            o0 += bf2f(u.x); o1 += bf2f(u.y); o2 += bf2f(u.z); o3 += bf2f(u.w);
        }
        ushort4 u;
        u.x = f2bf(o0 * rinv); u.y = f2bf(o1 * rinv);
        u.z = f2bf(o2 * rinv); u.w = f2bf(o3 * rinv);
        *(ushort4*)&Astage[row][col4] = u;
    }
    __syncthreads();

    // proj + residual + LN2 stats: wave w owns col = w*16+l15
    {
        int col = w * 16 + l15;
        f32x4 acc = (f32x4){0.f, 0.f, 0.f, 0.f};
        const unsigned short* bp = projT + (size_t)col * 256 + quad * 8;
        bf16x8 sb[4];
#pragma unroll
        for (int i = 0; i < 4; ++i) sb[i] = *(const bf16x8*)(bp + i * 32);
#pragma unroll
        for (int ch = 0; ch < 8; ++ch) {
            bf16x8 a = *(const bf16x8*)&Astage[l15 & 7][ch * 32 + quad * 8];
            acc = __builtin_amdgcn_mfma_f32_16x16x32_bf16(a, sb[ch & 3], acc, 0, 0, 0);
            if (ch + 4 < 8) sb[ch & 3] = *(const bf16x8*)(bp + (ch + 4) * 32);
        }
        float bs = proj_b[col];
#pragma unroll
        for (int r = 0; r < 4; ++r) {
            int row16 = quad * 4 + r;
            if (row16 < 8) {
                int grow = b * NB + qidx[(size_t)(slot0 + row16)];
                float v = (acc[r] + bs) + x[(size_t)grow * DIMM + col];   // mask==1 here
                x1s[row16][col] = v;
                float s = v, s2 = v * v;
#pragma unroll
                for (int off = 1; off < 16; off <<= 1) {
                    s += __shfl_xor(s, off); s2 += __shfl_xor(s2, off);
                }
                if (l15 == 0) { redn[row16][w][0] = s; redn[row16][w][1] = s2; }
            }
        }
    }
    __syncthreads();
    if (t < 8) {
        float s = 0.f, s2 = 0.f;
#pragma unroll
        for (int ww = 0; ww < 16; ++ww) { s += redn[t][ww][0]; s2 += redn[t][ww][1]; }
        float mean = s * (1.f / DIMM);
        float var  = s2 * (1.f / DIMM) - mean * mean;
        stats[t][0] = mean; stats[t][1] = rsqrtf(var + 1e-5f);
    }
    __syncthreads();

    // LN2 -> hstage
    {
        int col = w * 16 + l15;
        float gv = g2[col], bv = b2[col];
#pragma unroll
        for (int r = 0; r < 4; ++r) {
            int row16 = quad * 4 + r;
            if (row16 < 8) {
                float hv = (x1s[row16][col] - stats[row16][0]) * stats[row16][1] * gv + bv;
                hstage[row16][col] = f2bf(hv);
            }
        }
    }
    __syncthreads();

    // ffn1 + tanh-gelu: wave w owns cols w*64..w*64+63
    {
        f32x4 acc[4];
#pragma unroll
        for (int c = 0; c < 4; ++c) acc[c] = (f32x4){0.f, 0.f, 0.f, 0.f};
        const unsigned short* bp = f1T + (size_t)(w * 64 + l15) * 256 + quad * 8;
        bf16x8 bA[4], bB[4];
#pragma unroll
        for (int c = 0; c < 4; ++c) bA[c] = *(const bf16x8*)(bp + (size_t)(c * 16) * 256);
#pragma unroll
        for (int ch = 0; ch < 8; ++ch) {
            bf16x8 a = *(const bf16x8*)&hstage[l15 & 7][ch * 32 + quad * 8];
            if (ch + 1 < 8) {
#pragma unroll
                for (int c = 0; c < 4; ++c)
                    bB[c] = *(const bf16x8*)(bp + (size_t)(c * 16) * 256 + (ch + 1) * 32);
            }
#pragma unroll
            for (int c = 0; c < 4; ++c)
                acc[c] = __builtin_amdgcn_mfma_f32_16x16x32_bf16(a, bA[c], acc[c], 0, 0, 0);
#pragma unroll
            for (int c = 0; c < 4; ++c) bA[c] = bB[c];
        }
#pragma unroll
        for (int c = 0; c < 4; ++c) {
            int col = w * 64 + c * 16 + l15;
            float bs = ffn_b1[col];
#pragma unroll
            for (int r = 0; r < 4; ++r) {
                int row16 = quad * 4 + r;
                if (row16 < 8) {
                    float v = acc[c][r] + bs;
                    float x2 = v * v;
                    float p = v * fmaf(0.07135481f, x2, 1.5957691f);
                    float e = __expf(p);
                    float gl = v * (e / (e + 1.f));
                    midstage[row16][col] = f2bf(gl);
                }
            }
        }
    }
    __syncthreads();

    // ffn2 + final residual -> scatter out
    {
        int col = w * 16 + l15;
        f32x4 acc = (f32x4){0.f, 0.f, 0.f, 0.f};
        const unsigned short* bp = f2T + (size_t)col * 1024 + quad * 8;
        bf16x8 sb[4];
#pragma unroll
        for (int i = 0; i < 4; ++i) sb[i] = *(const bf16x8*)(bp + i * 32);
#pragma unroll
        for (int ch = 0; ch < 32; ++ch) {
            bf16x8 a = *(const bf16x8*)&midstage[l15 & 7][ch * 32 + quad * 8];
            acc = __builtin_amdgcn_mfma_f32_16x16x32_bf16(a, sb[ch & 3], acc, 0, 0, 0);
            if (ch + 4 < 32) sb[ch & 3] = *(const bf16x8*)(bp + (ch + 4) * 32);
        }
        float bs = ffn_b2[col];
#pragma unroll
        for (int r = 0; r < 4; ++r) {
            int row16 = quad * 4 + r;
            if (row16 < 8 && s0 + row16 < nvb) {
                int grow = b * NB + qidx[(size_t)(slot0 + row16)];
                out[(size_t)grow * DIMM + col] = x1s[row16][col] + (acc[r] + bs);
            }
        }
    }
}

// ---------------- launch ----------------
extern "C" void kernel_launch(void* const* d_in, const int* in_sizes, int n_in,
                              void* d_out, int out_size, void* d_ws, size_t ws_size,
                              hipStream_t stream) {
    const float* x       = (const float*)d_in[0];
    const int*   etypes  = (const int*)d_in[1];
    const void*  nmask   = d_in[2];
    const float* qkv_w   = (const float*)d_in[3];
    const float* qkv_b   = (const float*)d_in[4];
    const float* proj_w  = (const float*)d_in[5];
    const float* proj_b  = (const float*)d_in[6];
    const float* table   = (const float*)d_in[7];
    const float* ln1_g   = (const float*)d_in[8];
    const float* ln1_b   = (const float*)d_in[9];
    const float* ln2_g   = (const float*)d_in[10];
    const float* ln2_b   = (const float*)d_in[11];
    const float* ffn_w1  = (const float*)d_in[12];
    const float* ffn_b1  = (const float*)d_in[13];
    const float* ffn_w2  = (const float*)d_in[14];
    const float* ffn_b2  = (const float*)d_in[15];
    float* out = (float*)d_out;
    float* ws  = (float*)d_ws;

    float* lpart = ws;                               // 131,072 f (512 KB)
    unsigned short* ub = (unsigned short*)(ws + 131072);
    unsigned short* h_ln   = ub;                     // 1,048,576 us (compact)
    unsigned short* qkvh   = ub + 1048576;           // 2,097,152 (compact)
    unsigned short* vT     = ub + 3145728;           // 1,048,576 (compact)
    unsigned short* OpH    = ub + 4194304;           // 4,194,304 (compact, 4 splits)
    unsigned short* qkvT   = ub + 8388608;           // 196,608
    unsigned short* projT  = ub + 8585216;           // 65,536
    unsigned short* f1T    = ub + 8650752;           // 262,144
    unsigned short* f2T    = ub + 8912896;           // 262,144
    unsigned char* emaskP  = (unsigned char*)(ub + 9175040);  // 4,194,304 B
    unsigned short* qidx   = ub + 11272192;          // 4,096 us
    int* nv                = (int*)(ub + 11276288);  // 2 ints

    scan_w2bft_kernel<<<dim3(BB + 192), dim3(256), 0, stream>>>(
        nmask, nv, qidx, qkv_w, proj_w, ffn_w1, ffn_w2, qkvT, projT, f1T, f2T);
    prep_kernel<<<dim3(2560), dim3(256), 0, stream>>>(
        x, ln1_g, ln1_b, h_ln, etypes, emaskP, nv, qidx);
    gemm_qkv_mfma<<<dim3(12, 32, BB), dim3(256), 0, stream>>>(h_ln, qkvT, qkv_b, nv, qkvh, vT);
    attn_mfma<<<dim3(HEADS, NB/64, BB*4), dim3(256), 0, stream>>>(
        qkvh, vT, emaskP, table, nv, OpH, lpart);
    megaback<<<dim3(512 + ROWS/32), dim3(1024), 0, stream>>>(
        OpH, lpart, projT, proj_b, x, nmask, ln2_g, ln2_b,
        f1T, ffn_b1, f2T, ffn_b2, nv, qidx, out);
}

// Round 15
// 202.608 us; speedup vs baseline: 1.1411x; 1.1411x over previous
//
#include <hip/hip_runtime.h>
#include <math.h>

#define DIMM 256
#define HEADS 8
#define NB 2048
#define BB 2
#define ROWS (BB*NB)   // 4096

typedef __attribute__((ext_vector_type(8))) short bf16x8;
typedef __attribute__((ext_vector_type(4))) short bf16x4;
typedef __attribute__((ext_vector_type(4))) float f32x4;

__device__ inline unsigned short f2bf(float f) {
    unsigned int u = __float_as_uint(f);
    u += 0x7FFFu + ((u >> 16) & 1u);           // RNE
    return (unsigned short)(u >> 16);
}
__device__ inline float bf2f(unsigned short u) {
    return __uint_as_float(((unsigned int)u) << 16);
}

__device__ inline int get_mask(const void* nm, int fmt, int idx) {
    if (fmt) return ((const unsigned char*)nm)[idx] != 0;
    return ((const int*)nm)[idx] != 0;
}

// ---------------- scan (blocks 0..BB-1) + w2bfT (blocks BB..BB+191) ------------------
__global__ __launch_bounds__(256) void scan_w2bft_kernel(
    const void* __restrict__ nmask, int* __restrict__ nv,
    unsigned short* __restrict__ qidx,
    const float* __restrict__ w0, const float* __restrict__ w1,
    const float* __restrict__ w2, const float* __restrict__ w3,
    unsigned short* __restrict__ o0, unsigned short* __restrict__ o1,
    unsigned short* __restrict__ o2, unsigned short* __restrict__ o3)
{
    __shared__ float tile[64][65];
    __shared__ int fsh;
    __shared__ int cnt[256];
    __shared__ int base[256];
    int bid = blockIdx.x, t = threadIdx.x;
    if (bid < BB) {
        if (t == 0) fsh = 0;
        __syncthreads();
        if (((const unsigned char*)nmask)[4 * t + 1] != 0) fsh = 1;
        __syncthreads();
        int fm = fsh;
        int b = bid;
        int m[8]; int c = 0;
#pragma unroll
        for (int i = 0; i < 8; ++i) {
            m[i] = get_mask(nmask, fm, b * NB + t * 8 + i);
            c += m[i];
        }
        cnt[t] = c;
        __syncthreads();
        if (t == 0) {
            int acc = 0;
            for (int i = 0; i < 256; ++i) { base[i] = acc; acc += cnt[i]; }
            nv[b] = acc;
        }
        __syncthreads();
        int off = base[t];
#pragma unroll
        for (int i = 0; i < 8; ++i) {
            int row = t * 8 + i;
            if (m[i]) qidx[b * NB + off++] = (unsigned short)row;
        }
        __syncthreads();
        if (t == 0) {   // pad to multiple of 64 with last valid row (safe dup reads)
            int n = nv[b];
            unsigned short last = (n > 0) ? qidx[b * NB + n - 1] : (unsigned short)0;
            int padend = (n + 63) & ~63;
            for (int i = n; i < padend; ++i) qidx[b * NB + i] = last;
        }
    } else {
        int wb = bid - BB;
        const float* src; unsigned short* dst; int K, N, idx;
        if (wb < 48)       { src = w0; dst = o0; K = 256;  N = 768;  idx = wb; }
        else if (wb < 64)  { src = w1; dst = o1; K = 256;  N = 256;  idx = wb - 48; }
        else if (wb < 128) { src = w2; dst = o2; K = 256;  N = 1024; idx = wb - 64; }
        else               { src = w3; dst = o3; K = 1024; N = 256;  idx = wb - 128; }
        int ntiles = N >> 6;
        int k0 = (idx / ntiles) * 64, n0 = (idx % ntiles) * 64;
        int r = t >> 4, c4 = (t & 15) * 4;
#pragma unroll
        for (int i = 0; i < 4; ++i) {
            float4 v = *(const float4*)&src[(size_t)(k0 + r + i * 16) * N + n0 + c4];
            tile[r + i * 16][c4 + 0] = v.x;
            tile[r + i * 16][c4 + 1] = v.y;
            tile[r + i * 16][c4 + 2] = v.z;
            tile[r + i * 16][c4 + 3] = v.w;
        }
        __syncthreads();
#pragma unroll
        for (int i = 0; i < 4; ++i) {
            int n = n0 + r + i * 16;
            ushort4 u;
            u.x = f2bf(tile[c4 + 0][r + i * 16]);
            u.y = f2bf(tile[c4 + 1][r + i * 16]);
            u.z = f2bf(tile[c4 + 2][r + i * 16]);
            u.w = f2bf(tile[c4 + 3][r + i * 16]);
            *(ushort4*)&dst[(size_t)n * K + k0 + c4] = u;
        }
    }
}

// ---------------- LayerNorm body: read row xrow, write compact slot orow ----------
__device__ inline void ln8_body(const float* __restrict__ x, const float* __restrict__ g,
                                const float* __restrict__ bb, unsigned short* __restrict__ o,
                                int xrow, int orow, int lane32) {
    int c0 = lane32 * 8;
    float4 v0 = *(const float4*)&x[(size_t)xrow * DIMM + c0];
    float4 v1 = *(const float4*)&x[(size_t)xrow * DIMM + c0 + 4];
    float s  = v0.x + v0.y + v0.z + v0.w + v1.x + v1.y + v1.z + v1.w;
    float s2 = v0.x*v0.x + v0.y*v0.y + v0.z*v0.z + v0.w*v0.w
             + v1.x*v1.x + v1.y*v1.y + v1.z*v1.z + v1.w*v1.w;
#pragma unroll
    for (int off = 16; off >= 1; off >>= 1) {
        s  += __shfl_xor(s,  off);
        s2 += __shfl_xor(s2, off);
    }
    float mean = s * (1.0f / DIMM);
    float var  = s2 * (1.0f / DIMM) - mean * mean;
    float rstd = rsqrtf(var + 1e-5f);
    float4 g0 = *(const float4*)&g[c0],  g1 = *(const float4*)&g[c0 + 4];
    float4 b0 = *(const float4*)&bb[c0], b1 = *(const float4*)&bb[c0 + 4];
    ushort4 u0, u1;
    u0.x = f2bf((v0.x - mean) * rstd * g0.x + b0.x);
    u0.y = f2bf((v0.y - mean) * rstd * g0.y + b0.y);
    u0.z = f2bf((v0.z - mean) * rstd * g0.z + b0.z);
    u0.w = f2bf((v0.w - mean) * rstd * g0.w + b0.w);
    u1.x = f2bf((v1.x - mean) * rstd * g1.x + b1.x);
    u1.y = f2bf((v1.y - mean) * rstd * g1.y + b1.y);
    u1.z = f2bf((v1.z - mean) * rstd * g1.z + b1.z);
    u1.w = f2bf((v1.w - mean) * rstd * g1.w + b1.w);
    *(ushort4*)&o[(size_t)orow * DIMM + c0]     = u0;
    *(ushort4*)&o[(size_t)orow * DIMM + c0 + 4] = u1;
}

// ---------------- prep: compact LN1 (0..511) + emaskP (512..2559) --------------------
__global__ __launch_bounds__(256) void prep_kernel(
    const float* __restrict__ x, const float* __restrict__ ln1_g,
    const float* __restrict__ ln1_b, unsigned short* __restrict__ h_ln,
    const int* __restrict__ etypes,
    unsigned char* __restrict__ emaskP,
    const int* __restrict__ nv, const unsigned short* __restrict__ qidx)
{
    int bid = blockIdx.x, t = threadIdx.x;
    if (bid < 512) {
        int slotg = bid * 8 + (t >> 5);
        int b = slotg >> 11, sl = slotg & 2047;
        int nvp = (nv[b] + 63) & ~63;
        if (sl < nvp) {
            int row = qidx[b * NB + sl];
            ln8_body(x, ln1_g, ln1_b, h_ln, b * NB + row, slotg, t & 31);
        }
    } else {
        int unit = (bid - 512) * 4 + (t >> 6);
        int lane = t & 63, quad = lane >> 4, l15 = lane & 15;
        int b = unit >> 12;
        int qt16 = (unit >> 5) & 127;
        int kt = unit & 31;
        int nvb = nv[b];
        int nvp = (nvb + 63) & ~63;
        if (qt16 * 16 >= nvb || kt * 64 >= nvp) return;
        int slot = qt16 * 16 + l15;
        int validq = slot < nvb;
        int qr = qidx[b * NB + slot];
        const int* erow = etypes + (size_t)(b * NB + qr) * NB;
        unsigned int dw[2] = {0u, 0u};
#pragma unroll
        for (int t16 = 0; t16 < 4; ++t16) {
#pragma unroll
            for (int r = 0; r < 4; ++r) {
                int ks = kt * 64 + t16 * 16 + quad * 4 + r;
                unsigned int code = 0u;
                if (validq && ks < nvb) {
                    int korig = qidx[b * NB + ks];
                    int et = erow[korig];
                    if ((et != 0) || (korig == qr)) code = (unsigned int)(et + 1);
                }
                dw[t16 >> 1] |= code << ((t16 & 1) * 16 + r * 4);
            }
        }
        int2 o = {(int)dw[0], (int)dw[1]};
        *(int2*)(emaskP + (size_t)unit * 512 + lane * 8) = o;
    }
}

// ---------------- compact qkv GEMM (64x64); q pre-scaled; per-batch grid -------------
__global__ __launch_bounds__(256) void gemm_qkv_mfma(
    const unsigned short* __restrict__ A, const unsigned short* __restrict__ Bt,
    const float* __restrict__ bias, const int* __restrict__ nv,
    unsigned short* __restrict__ qkvh, unsigned short* __restrict__ vT)
{
    const int K = 256;
    int t = threadIdx.x, w = t >> 6, l = t & 63;
    int l15 = l & 15, quad = l >> 4;
    int n0 = blockIdx.x * 64;
    int m0c = blockIdx.y * 64;
    int b = blockIdx.z;
    int nvp = (nv[b] + 63) & ~63;
    if (m0c >= nvp) return;
    const unsigned short* ap = A + (size_t)(b * NB + m0c + w * 16 + l15) * K + quad * 8;
    const unsigned short* bp = Bt + (size_t)(n0 + l15) * K + quad * 8;

    f32x4 acc[4];
#pragma unroll
    for (int c = 0; c < 4; ++c) acc[c] = (f32x4){0.f, 0.f, 0.f, 0.f};

    bf16x8 aA, bA[4], aB, bB[4];
    auto ld = [&](bf16x8& af, bf16x8 (&bf)[4], int k0) {
        af = *(const bf16x8*)(ap + k0);
#pragma unroll
        for (int c = 0; c < 4; ++c)
            bf[c] = *(const bf16x8*)(bp + (size_t)(c * 16) * K + k0);
    };
    auto pr = [&](const bf16x8& af, const bf16x8 (&bf)[4]) {
#pragma unroll
        for (int c = 0; c < 4; ++c)
            acc[c] = __builtin_amdgcn_mfma_f32_16x16x32_bf16(af, bf[c], acc[c], 0, 0, 0);
    };
    ld(aA, bA, 0);
    for (int k0 = 0; k0 < K; k0 += 64) {
        ld(aB, bB, k0 + 32);
        pr(aA, bA);
        if (k0 + 64 < K) ld(aA, bA, k0 + 64);
        pr(aB, bB);
    }

    if (n0 < 512) {
        float sc = (n0 < 256) ? 0.17677669529663689f : 1.0f;   // fold 1/sqrt(32) into q
#pragma unroll
        for (int r = 0; r < 4; ++r) {
            int slot = b * NB + m0c + w * 16 + quad * 4 + r;
#pragma unroll
            for (int c = 0; c < 4; ++c) {
                int col = n0 + c * 16 + l15;
                qkvh[(size_t)slot * 512 + col] = f2bf((acc[c][r] + bias[col]) * sc);
            }
        }
    } else {
        int n = m0c + w * 16 + quad * 4;
#pragma unroll
        for (int c = 0; c < 4; ++c) {
            int col = n0 + c * 16 + l15 - 512;
            int hidx = col >> 5, d = col & 31;
            float bs = bias[n0 + c * 16 + l15];
            ushort4 u;
            u.x = f2bf(acc[c][0] + bs);
            u.y = f2bf(acc[c][1] + bs);
            u.z = f2bf(acc[c][2] + bs);
            u.w = f2bf(acc[c][3] + bs);
            *(ushort4*)&vT[(size_t)((b * HEADS + hidx) * 32 + d) * NB + n] = u;
        }
    }
}

// ---------------- MFMA attention: fully compact (q AND k), S^T + b64 P + R6 PV -------
__global__ __launch_bounds__(256) void attn_mfma(
    const unsigned short* __restrict__ qkvh,
    const unsigned short* __restrict__ vT,
    const unsigned char* __restrict__ emaskP,
    const float* __restrict__ table,
    const int* __restrict__ nv,
    unsigned short* __restrict__ OpH, float* __restrict__ lpart)
{
    __shared__ unsigned short P[4][16][72];
    __shared__ float tab2m[16];

    int t = threadIdx.x;
    int w = t >> 6, l = t & 63;
    int l15 = l & 15, quad = l >> 4;
    int h = blockIdx.x;
    int qt = blockIdx.y;
    int z = blockIdx.z, b = z >> 2, sp = z & 3;

    if (t < 16) tab2m[t] = (t >= 1 && t < 10) ? __expf(table[(t - 1) * 8 + h]) : 0.f;
    __syncthreads();

    int nvb = nv[b];
    int qt16 = qt * 4 + w;
    int q0c = qt16 * 16;
    if (q0c >= nvb) return;

    int nkt = (nvb + 63) >> 6;
    int tps = (nkt + 3) >> 2;
    int kbase = sp * tps * 64;
    int kend = min(kbase + tps * 64, nkt * 64);

    bf16x8 bq = *(const bf16x8*)(qkvh + (size_t)(b * NB + q0c + l15) * 512 + h * 32 + quad * 8);

    const unsigned short* kp = qkvh + (size_t)(b * NB + l15) * 512 + 256 + h * 32 + quad * 8;
    const unsigned short* vp = vT + (size_t)((b * HEADS + h) * 32 + l15) * NB + quad * 8;
    const unsigned char* ep = emaskP + (size_t)((b * 128 + qt16) * 32) * 512 + l * 8;

    float lacc = 0.f;
    f32x4 O0 = {0.f, 0.f, 0.f, 0.f}, O1 = {0.f, 0.f, 0.f, 0.f};

    bf16x8 kA[4], kB[4];
    bf16x8 vA[2][2], vB[2][2];
    int2 eA, eB;

    auto loadtile = [&](bf16x8 (&kf)[4], bf16x8 (&vf)[2][2], int2& ef, int m0) {
#pragma unroll
        for (int t16 = 0; t16 < 4; ++t16)
            kf[t16] = *(const bf16x8*)(kp + (size_t)(m0 + t16 * 16) * 512);
#pragma unroll
        for (int ks = 0; ks < 2; ++ks) {
            vf[ks][0] = *(const bf16x8*)(vp + m0 + ks * 32);
            vf[ks][1] = *(const bf16x8*)(vp + 16 * NB + m0 + ks * 32);
        }
        ef = *(const int2*)(ep + (size_t)(m0 >> 6) * 512);
    };

    auto process = [&](const bf16x8 (&kf)[4], const bf16x8 (&vf)[2][2], const int2& ef) {
#pragma unroll
        for (int t16 = 0; t16 < 4; ++t16) {
            f32x4 zero = {0.f, 0.f, 0.f, 0.f};
            f32x4 sT = __builtin_amdgcn_mfma_f32_16x16x32_bf16(kf[t16], bq, zero, 0, 0, 0);
            unsigned int e = ((unsigned int)((t16 < 2) ? ef.x : ef.y)) >> ((t16 & 1) * 16);
            float p0 = __expf(sT[0]) * tab2m[e & 0xFu];
            float p1 = __expf(sT[1]) * tab2m[(e >> 4) & 0xFu];
            float p2 = __expf(sT[2]) * tab2m[(e >> 8) & 0xFu];
            float p3 = __expf(sT[3]) * tab2m[(e >> 12) & 0xFu];
            lacc += (p0 + p1) + (p2 + p3);
            bf16x4 pb;
            pb[0] = (short)f2bf(p0); pb[1] = (short)f2bf(p1);
            pb[2] = (short)f2bf(p2); pb[3] = (short)f2bf(p3);
            *(bf16x4*)&P[w][l15][t16 * 16 + quad * 4] = pb;
        }
#pragma unroll
        for (int ks = 0; ks < 2; ++ks) {
            bf16x8 pa = *(const bf16x8*)&P[w][l15][ks * 32 + quad * 8];
            O0 = __builtin_amdgcn_mfma_f32_16x16x32_bf16(pa, vf[ks][0], O0, 0, 0, 0);
            O1 = __builtin_amdgcn_mfma_f32_16x16x32_bf16(pa, vf[ks][1], O1, 0, 0, 0);
        }
    };

    if (kbase < kend) {
        loadtile(kA, vA, eA, kbase);
        for (int m0 = kbase; m0 < kend; m0 += 128) {
            int n1 = (m0 + 64 < kend) ? m0 + 64 : kbase;
            loadtile(kB, vB, eB, n1);
            process(kA, vA, eA);
            if (m0 + 128 < kend) loadtile(kA, vA, eA, m0 + 128);
            if (m0 + 64 < kend) process(kB, vB, eB);
        }
    }

    lacc += __shfl_xor(lacc, 16);
    lacc += __shfl_xor(lacc, 32);

    unsigned short* Ob = OpH + (size_t)sp * ROWS * DIMM;
#pragma unroll
    for (int r = 0; r < 4; ++r) {
        int slot = q0c + quad * 4 + r;
        if (slot < nvb) {
            Ob[(size_t)(b * NB + slot) * DIMM + h * 32 + l15]      = f2bf(O0[r]);
            Ob[(size_t)(b * NB + slot) * DIMM + h * 32 + 16 + l15] = f2bf(O1[r]);
        }
    }
    if (quad == 0 && q0c + l15 < nvb)
        lpart[(size_t)sp * ROWS * 8 + (size_t)(b * NB + q0c + l15) * 8 + h] = lacc;
}

// ---------------- megaback: 16-row compute (0..255, R13-proven) + masked copy (256..) -
__global__ __launch_bounds__(1024) void megaback(
    const unsigned short* __restrict__ OpH, const float* __restrict__ lpart,
    const unsigned short* __restrict__ projT, const float* __restrict__ proj_b,
    const float* __restrict__ x, const void* __restrict__ nmask,
    const float* __restrict__ g2, const float* __restrict__ b2,
    const unsigned short* __restrict__ f1T, const float* __restrict__ ffn_b1,
    const unsigned short* __restrict__ f2T, const float* __restrict__ ffn_b2,
    const int* __restrict__ nv, const unsigned short* __restrict__ qidx,
    float* __restrict__ out)
{
    __shared__ float rinv_l[16][8];
    __shared__ float stats[16][2];
    __shared__ float redn[16][16][2];
    __shared__ unsigned short Astage[16][264];
    __shared__ float x1s[16][260];
    __shared__ unsigned short hstage[16][264];
    __shared__ unsigned short midstage[16][1032];
    __shared__ int fsh;

    int t = threadIdx.x;
    int bid = blockIdx.x;

    if (bid >= 256) {
        // masked-row copy: out[row] = x[row] (proj*0, ffn*0 => exact)
        if (t == 0) fsh = 0;
        __syncthreads();
        if (((const unsigned char*)nmask)[4 * t + 1] != 0) fsh = 1;
        __syncthreads();
        int fm = fsh;
        int row = (bid - 256) * 32 + (t >> 5);
        if (!get_mask(nmask, fm, row)) {
            int c0 = (t & 31) * 8;
            float4 v0 = *(const float4*)&x[(size_t)row * DIMM + c0];
            float4 v1 = *(const float4*)&x[(size_t)row * DIMM + c0 + 4];
            *(float4*)&out[(size_t)row * DIMM + c0]     = v0;
            *(float4*)&out[(size_t)row * DIMM + c0 + 4] = v1;
        }
        return;
    }

    int w = t >> 6, l = t & 63;
    int l15 = l & 15, quad = l >> 4;
    int b = bid >> 7;
    int s0 = (bid & 127) * 16;
    int nvb = nv[b];
    if (s0 >= nvb) return;                    // block-uniform, before barriers
    int slot0 = b * NB + s0;

    if (t < 128) {
        int row = t >> 3, h = t & 7;
        float s = 0.f;
#pragma unroll
        for (int sp = 0; sp < 4; ++sp)
            s += lpart[(size_t)sp * ROWS * 8 + (size_t)(slot0 + row) * 8 + h];
        rinv_l[row][h] = (s > 0.f) ? 1.f / s : 0.f;
    }
    __syncthreads();

    {
        int row = t >> 6, col4 = (t & 63) * 4;
        float rinv = rinv_l[row][col4 >> 5];
        float o0 = 0.f, o1 = 0.f, o2 = 0.f, o3 = 0.f;
#pragma unroll
        for (int sp = 0; sp < 4; ++sp) {
            ushort4 u = *(const ushort4*)&OpH[(size_t)sp * ROWS * DIMM +
                                             (size_t)(slot0 + row) * DIMM + col4];
            o0 += bf2f(u.x); o1 += bf2f(u.y); o2 += bf2f(u.z); o3 += bf2f(u.w);
        }
        ushort4 u;
        u.x = f2bf(o0 * rinv); u.y = f2bf(o1 * rinv);
        u.z = f2bf(o2 * rinv); u.w = f2bf(o3 * rinv);
        *(ushort4*)&Astage[row][col4] = u;
    }
    __syncthreads();

    {
        int col = w * 16 + l15;
        f32x4 acc = (f32x4){0.f, 0.f, 0.f, 0.f};
        const unsigned short* bp = projT + (size_t)col * 256 + quad * 8;
        bf16x8 sb[4];
#pragma unroll
        for (int i = 0; i < 4; ++i) sb[i] = *(const bf16x8*)(bp + i * 32);
#pragma unroll
        for (int ch = 0; ch < 8; ++ch) {
            bf16x8 a = *(const bf16x8*)&Astage[l15][ch * 32 + quad * 8];
            acc = __builtin_amdgcn_mfma_f32_16x16x32_bf16(a, sb[ch & 3], acc, 0, 0, 0);
            if (ch + 4 < 8) sb[ch & 3] = *(const bf16x8*)(bp + (ch + 4) * 32);
        }
        float bs = proj_b[col];
#pragma unroll
        for (int r = 0; r < 4; ++r) {
            int row = quad * 4 + r;
            int grow = b * NB + qidx[(size_t)(slot0 + row)];
            float v = (acc[r] + bs) + x[(size_t)grow * DIMM + col];   // mask==1 here
            x1s[row][col] = v;
            float s = v, s2 = v * v;
#pragma unroll
            for (int off = 1; off < 16; off <<= 1) {
                s += __shfl_xor(s, off); s2 += __shfl_xor(s2, off);
            }
            if (l15 == 0) { redn[row][w][0] = s; redn[row][w][1] = s2; }
        }
    }
    __syncthreads();
    if (t < 16) {
        float s = 0.f, s2 = 0.f;
#pragma unroll
        for (int ww = 0; ww < 16; ++ww) { s += redn[t][ww][0]; s2 += redn[t][ww][1]; }
        float mean = s * (1.f / DIMM);
        float var  = s2 * (1.f / DIMM) - mean * mean;
        stats[t][0] = mean; stats[t][1] = rsqrtf(var + 1e-5f);
    }
    __syncthreads();

    {
        int col = w * 16 + l15;
        float gv = g2[col], bv = b2[col];
#pragma unroll
        for (int r = 0; r < 4; ++r) {
            int row = quad * 4 + r;
            float hv = (x1s[row][col] - stats[row][0]) * stats[row][1] * gv + bv;
            hstage[row][col] = f2bf(hv);
        }
    }
    __syncthreads();

    {
        f32x4 acc[4];
#pragma unroll
        for (int c = 0; c < 4; ++c) acc[c] = (f32x4){0.f, 0.f, 0.f, 0.f};
        const unsigned short* bp = f1T + (size_t)(w * 64 + l15) * 256 + quad * 8;
        bf16x8 bA[4], bB[4];
#pragma unroll
        for (int c = 0; c < 4; ++c) bA[c] = *(const bf16x8*)(bp + (size_t)(c * 16) * 256);
#pragma unroll
        for (int ch = 0; ch < 8; ++ch) {
            bf16x8 a = *(const bf16x8*)&hstage[l15][ch * 32 + quad * 8];
            if (ch + 1 < 8) {
#pragma unroll
                for (int c = 0; c < 4; ++c)
                    bB[c] = *(const bf16x8*)(bp + (size_t)(c * 16) * 256 + (ch + 1) * 32);
            }
#pragma unroll
            for (int c = 0; c < 4; ++c)
                acc[c] = __builtin_amdgcn_mfma_f32_16x16x32_bf16(a, bA[c], acc[c], 0, 0, 0);
#pragma unroll
            for (int c = 0; c < 4; ++c) bA[c] = bB[c];
        }
#pragma unroll
        for (int c = 0; c < 4; ++c) {
            int col = w * 64 + c * 16 + l15;
            float bs = ffn_b1[col];
#pragma unroll
            for (int r = 0; r < 4; ++r) {
                float v = acc[c][r] + bs;
                float x2 = v * v;
                float p = v * fmaf(0.07135481f, x2, 1.5957691f);
                float e = __expf(p);
                float gl = v * (e / (e + 1.f));
                midstage[quad * 4 + r][col] = f2bf(gl);
            }
        }
    }
    __syncthreads();

    {
        int col = w * 16 + l15;
        f32x4 acc = (f32x4){0.f, 0.f, 0.f, 0.f};
        const unsigned short* bp = f2T + (size_t)col * 1024 + quad * 8;
        bf16x8 sb[4];
#pragma unroll
        for (int i = 0; i < 4; ++i) sb[i] = *(const bf16x8*)(bp + i * 32);
#pragma unroll
        for (int ch = 0; ch < 32; ++ch) {
            bf16x8 a = *(const bf16x8*)&midstage[l15][ch * 32 + quad * 8];
            acc = __builtin_amdgcn_mfma_f32_16x16x32_bf16(a, sb[ch & 3], acc, 0, 0, 0);
            if (ch + 4 < 32) sb[ch & 3] = *(const bf16x8*)(bp + (ch + 4) * 32);
        }
        float bs = ffn_b2[col];
#pragma unroll
        for (int r = 0; r < 4; ++r) {
            int row = quad * 4 + r;
            if (s0 + row < nvb) {
                int grow = b * NB + qidx[(size_t)(slot0 + row)];
                out[(size_t)grow * DIMM + col] = x1s[row][col] + (acc[r] + bs);
            }
        }
    }
}

// ---------------- launch ----------------
extern "C" void kernel_launch(void* const* d_in, const int* in_sizes, int n_in,
                              void* d_out, int out_size, void* d_ws, size_t ws_size,
                              hipStream_t stream) {
    const float* x       = (const float*)d_in[0];
    const int*   etypes  = (const int*)d_in[1];
    const void*  nmask   = d_in[2];
    const float* qkv_w   = (const float*)d_in[3];
    const float* qkv_b   = (const float*)d_in[4];
    const float* proj_w  = (const float*)d_in[5];
    const float* proj_b  = (const float*)d_in[6];
    const float* table   = (const float*)d_in[7];
    const float* ln1_g   = (const float*)d_in[8];
    const float* ln1_b   = (const float*)d_in[9];
    const float* ln2_g   = (const float*)d_in[10];
    const float* ln2_b   = (const float*)d_in[11];
    const float* ffn_w1  = (const float*)d_in[12];
    const float* ffn_b1  = (const float*)d_in[13];
    const float* ffn_w2  = (const float*)d_in[14];
    const float* ffn_b2  = (const float*)d_in[15];
    float* out = (float*)d_out;
    float* ws  = (float*)d_ws;

    float* lpart = ws;                               // 131,072 f (512 KB)
    unsigned short* ub = (unsigned short*)(ws + 131072);
    unsigned short* h_ln   = ub;                     // 1,048,576 us (compact)
    unsigned short* qkvh   = ub + 1048576;           // 2,097,152 (compact)
    unsigned short* vT     = ub + 3145728;           // 1,048,576 (compact)
    unsigned short* OpH    = ub + 4194304;           // 4,194,304 (compact, 4 splits)
    unsigned short* qkvT   = ub + 8388608;           // 196,608
    unsigned short* projT  = ub + 8585216;           // 65,536
    unsigned short* f1T    = ub + 8650752;           // 262,144
    unsigned short* f2T    = ub + 8912896;           // 262,144
    unsigned char* emaskP  = (unsigned char*)(ub + 9175040);  // 4,194,304 B
    unsigned short* qidx   = ub + 11272192;          // 4,096 us
    int* nv                = (int*)(ub + 11276288);  // 2 ints

    scan_w2bft_kernel<<<dim3(BB + 192), dim3(256), 0, stream>>>(
        nmask, nv, qidx, qkv_w, proj_w, ffn_w1, ffn_w2, qkvT, projT, f1T, f2T);
    prep_kernel<<<dim3(2560), dim3(256), 0, stream>>>(
        x, ln1_g, ln1_b, h_ln, etypes, emaskP, nv, qidx);
    gemm_qkv_mfma<<<dim3(12, 32, BB), dim3(256), 0, stream>>>(h_ln, qkvT, qkv_b, nv, qkvh, vT);
    attn_mfma<<<dim3(HEADS, NB/64, BB*4), dim3(256), 0, stream>>>(
        qkvh, vT, emaskP, table, nv, OpH, lpart);
    megaback<<<dim3(256 + ROWS/32), dim3(1024), 0, stream>>>(
        OpH, lpart, projT, proj_b, x, nmask, ln2_g, ln2_b,
        f1T, ffn_b1, f2T, ffn_b2, nv, qidx, out);
}

// Round 16
// 193.555 us; speedup vs baseline: 1.1944x; 1.0468x over previous
//
#include <hip/hip_runtime.h>
#include <math.h>

#define DIMM 256
#define HEADS 8
#define NB 2048
#define BB 2
#define ROWS (BB*NB)   // 4096

typedef __attribute__((ext_vector_type(8))) short bf16x8;
typedef __attribute__((ext_vector_type(4))) short bf16x4;
typedef __attribute__((ext_vector_type(4))) float f32x4;

__device__ inline unsigned short f2bf(float f) {
    unsigned int u = __float_as_uint(f);
    u += 0x7FFFu + ((u >> 16) & 1u);           // RNE
    return (unsigned short)(u >> 16);
}
__device__ inline float bf2f(unsigned short u) {
    return __uint_as_float(((unsigned int)u) << 16);
}

__device__ inline int get_mask(const void* nm, int fmt, int idx) {
    if (fmt) return ((const unsigned char*)nm)[idx] != 0;
    return ((const int*)nm)[idx] != 0;
}

// ---------------- scan (blocks 0..BB-1, parallel prefix) + w2bfT (BB..BB+191) --------
__global__ __launch_bounds__(256) void scan_w2bft_kernel(
    const void* __restrict__ nmask, int* __restrict__ nv,
    unsigned short* __restrict__ qidx,
    const float* __restrict__ w0, const float* __restrict__ w1,
    const float* __restrict__ w2, const float* __restrict__ w3,
    unsigned short* __restrict__ o0, unsigned short* __restrict__ o1,
    unsigned short* __restrict__ o2, unsigned short* __restrict__ o3)
{
    __shared__ float tile[64][65];
    __shared__ int fsh;
    __shared__ int cnt[256];
    int bid = blockIdx.x, t = threadIdx.x;
    if (bid < BB) {
        if (t == 0) fsh = 0;
        __syncthreads();
        if (((const unsigned char*)nmask)[4 * t + 1] != 0) fsh = 1;
        __syncthreads();
        int fm = fsh;
        int b = bid;
        int m[8]; int c = 0;
#pragma unroll
        for (int i = 0; i < 8; ++i) {
            m[i] = get_mask(nmask, fm, b * NB + t * 8 + i);
            c += m[i];
        }
        cnt[t] = c;
        __syncthreads();
        // Hillis-Steele inclusive scan over 256 entries
#pragma unroll
        for (int off = 1; off < 256; off <<= 1) {
            int v = (t >= off) ? cnt[t - off] : 0;
            __syncthreads();
            cnt[t] += v;
            __syncthreads();
        }
        int mybase = cnt[t] - c;
        if (t == 255) nv[b] = cnt[255];
        int off = mybase;
#pragma unroll
        for (int i = 0; i < 8; ++i) {
            int row = t * 8 + i;
            if (m[i]) qidx[b * NB + off++] = (unsigned short)row;
        }
        __syncthreads();
        if (t == 0) {   // pad to multiple of 64 with last valid row (safe dup reads)
            int n = cnt[255];
            unsigned short last = (n > 0) ? qidx[b * NB + n - 1] : (unsigned short)0;
            int padend = (n + 63) & ~63;
            for (int i = n; i < padend; ++i) qidx[b * NB + i] = last;
        }
    } else {
        int wb = bid - BB;
        const float* src; unsigned short* dst; int K, N, idx;
        if (wb < 48)       { src = w0; dst = o0; K = 256;  N = 768;  idx = wb; }
        else if (wb < 64)  { src = w1; dst = o1; K = 256;  N = 256;  idx = wb - 48; }
        else if (wb < 128) { src = w2; dst = o2; K = 256;  N = 1024; idx = wb - 64; }
        else               { src = w3; dst = o3; K = 1024; N = 256;  idx = wb - 128; }
        int ntiles = N >> 6;
        int k0 = (idx / ntiles) * 64, n0 = (idx % ntiles) * 64;
        int r = t >> 4, c4 = (t & 15) * 4;
#pragma unroll
        for (int i = 0; i < 4; ++i) {
            float4 v = *(const float4*)&src[(size_t)(k0 + r + i * 16) * N + n0 + c4];
            tile[r + i * 16][c4 + 0] = v.x;
            tile[r + i * 16][c4 + 1] = v.y;
            tile[r + i * 16][c4 + 2] = v.z;
            tile[r + i * 16][c4 + 3] = v.w;
        }
        __syncthreads();
#pragma unroll
        for (int i = 0; i < 4; ++i) {
            int n = n0 + r + i * 16;
            ushort4 u;
            u.x = f2bf(tile[c4 + 0][r + i * 16]);
            u.y = f2bf(tile[c4 + 1][r + i * 16]);
            u.z = f2bf(tile[c4 + 2][r + i * 16]);
            u.w = f2bf(tile[c4 + 3][r + i * 16]);
            *(ushort4*)&dst[(size_t)n * K + k0 + c4] = u;
        }
    }
}

// ---------------- LayerNorm body: read row xrow, write compact slot orow ----------
__device__ inline void ln8_body(const float* __restrict__ x, const float* __restrict__ g,
                                const float* __restrict__ bb, unsigned short* __restrict__ o,
                                int xrow, int orow, int lane32) {
    int c0 = lane32 * 8;
    float4 v0 = *(const float4*)&x[(size_t)xrow * DIMM + c0];
    float4 v1 = *(const float4*)&x[(size_t)xrow * DIMM + c0 + 4];
    float s  = v0.x + v0.y + v0.z + v0.w + v1.x + v1.y + v1.z + v1.w;
    float s2 = v0.x*v0.x + v0.y*v0.y + v0.z*v0.z + v0.w*v0.w
             + v1.x*v1.x + v1.y*v1.y + v1.z*v1.z + v1.w*v1.w;
#pragma unroll
    for (int off = 16; off >= 1; off >>= 1) {
        s  += __shfl_xor(s,  off);
        s2 += __shfl_xor(s2, off);
    }
    float mean = s * (1.0f / DIMM);
    float var  = s2 * (1.0f / DIMM) - mean * mean;
    float rstd = rsqrtf(var + 1e-5f);
    float4 g0 = *(const float4*)&g[c0],  g1 = *(const float4*)&g[c0 + 4];
    float4 b0 = *(const float4*)&bb[c0], b1 = *(const float4*)&bb[c0 + 4];
    ushort4 u0, u1;
    u0.x = f2bf((v0.x - mean) * rstd * g0.x + b0.x);
    u0.y = f2bf((v0.y - mean) * rstd * g0.y + b0.y);
    u0.z = f2bf((v0.z - mean) * rstd * g0.z + b0.z);
    u0.w = f2bf((v0.w - mean) * rstd * g0.w + b0.w);
    u1.x = f2bf((v1.x - mean) * rstd * g1.x + b1.x);
    u1.y = f2bf((v1.y - mean) * rstd * g1.y + b1.y);
    u1.z = f2bf((v1.z - mean) * rstd * g1.z + b1.z);
    u1.w = f2bf((v1.w - mean) * rstd * g1.w + b1.w);
    *(ushort4*)&o[(size_t)orow * DIMM + c0]     = u0;
    *(ushort4*)&o[(size_t)orow * DIMM + c0 + 4] = u1;
}

// ---------------- prep: compact LN1 (0..511) + emaskP (512..2559) --------------------
__global__ __launch_bounds__(256) void prep_kernel(
    const float* __restrict__ x, const float* __restrict__ ln1_g,
    const float* __restrict__ ln1_b, unsigned short* __restrict__ h_ln,
    const int* __restrict__ etypes,
    unsigned char* __restrict__ emaskP,
    const int* __restrict__ nv, const unsigned short* __restrict__ qidx)
{
    __shared__ unsigned short kq[4][64];   // per-wave staged key-slot origins
    int bid = blockIdx.x, t = threadIdx.x;
    if (bid < 512) {
        int slotg = bid * 8 + (t >> 5);
        int b = slotg >> 11, sl = slotg & 2047;
        int nvp = (nv[b] + 63) & ~63;
        if (sl < nvp) {
            int row = qidx[b * NB + sl];
            ln8_body(x, ln1_g, ln1_b, h_ln, b * NB + row, slotg, t & 31);
        }
    } else {
        int wu = t >> 6;
        int unit = (bid - 512) * 4 + wu;
        int lane = t & 63, quad = lane >> 4, l15 = lane & 15;
        int b = unit >> 12;
        int qt16 = (unit >> 5) & 127;
        int kt = unit & 31;
        int nvb = nv[b];
        int nvp = (nvb + 63) & ~63;
        if (qt16 * 16 >= nvb || kt * 64 >= nvp) return;
        // stage this unit's 64 key origins: one coalesced lane-load (same-wave LDS)
        kq[wu][lane] = qidx[b * NB + kt * 64 + lane];
        int slot = qt16 * 16 + l15;
        int validq = slot < nvb;
        int qr = qidx[b * NB + slot];
        const int* erow = etypes + (size_t)(b * NB + qr) * NB;
        unsigned int dw[2] = {0u, 0u};
#pragma unroll
        for (int t16 = 0; t16 < 4; ++t16) {
            ushort4 ko = *(const ushort4*)&kq[wu][t16 * 16 + quad * 4];
            unsigned short kos[4] = {ko.x, ko.y, ko.z, ko.w};
#pragma unroll
            for (int r = 0; r < 4; ++r) {
                int ks = kt * 64 + t16 * 16 + quad * 4 + r;
                unsigned int code = 0u;
                if (validq && ks < nvb) {
                    int korig = kos[r];
                    int et = erow[korig];
                    if ((et != 0) || (korig == qr)) code = (unsigned int)(et + 1);
                }
                dw[t16 >> 1] |= code << ((t16 & 1) * 16 + r * 4);
            }
        }
        int2 o = {(int)dw[0], (int)dw[1]};
        *(int2*)(emaskP + (size_t)unit * 512 + lane * 8) = o;
    }
}

// ---------------- compact qkv GEMM (64x64); q pre-scaled; per-batch grid -------------
__global__ __launch_bounds__(256) void gemm_qkv_mfma(
    const unsigned short* __restrict__ A, const unsigned short* __restrict__ Bt,
    const float* __restrict__ bias, const int* __restrict__ nv,
    unsigned short* __restrict__ qkvh, unsigned short* __restrict__ vT)
{
    const int K = 256;
    int t = threadIdx.x, w = t >> 6, l = t & 63;
    int l15 = l & 15, quad = l >> 4;
    int n0 = blockIdx.x * 64;
    int m0c = blockIdx.y * 64;
    int b = blockIdx.z;
    int nvp = (nv[b] + 63) & ~63;
    if (m0c >= nvp) return;
    const unsigned short* ap = A + (size_t)(b * NB + m0c + w * 16 + l15) * K + quad * 8;
    const unsigned short* bp = Bt + (size_t)(n0 + l15) * K + quad * 8;

    f32x4 acc[4];
#pragma unroll
    for (int c = 0; c < 4; ++c) acc[c] = (f32x4){0.f, 0.f, 0.f, 0.f};

    bf16x8 aA, bA[4], aB, bB[4];
    auto ld = [&](bf16x8& af, bf16x8 (&bf)[4], int k0) {
        af = *(const bf16x8*)(ap + k0);
#pragma unroll
        for (int c = 0; c < 4; ++c)
            bf[c] = *(const bf16x8*)(bp + (size_t)(c * 16) * K + k0);
    };
    auto pr = [&](const bf16x8& af, const bf16x8 (&bf)[4]) {
#pragma unroll
        for (int c = 0; c < 4; ++c)
            acc[c] = __builtin_amdgcn_mfma_f32_16x16x32_bf16(af, bf[c], acc[c], 0, 0, 0);
    };
    ld(aA, bA, 0);
    for (int k0 = 0; k0 < K; k0 += 64) {
        ld(aB, bB, k0 + 32);
        pr(aA, bA);
        if (k0 + 64 < K) ld(aA, bA, k0 + 64);
        pr(aB, bB);
    }

    if (n0 < 512) {
        float sc = (n0 < 256) ? 0.17677669529663689f : 1.0f;   // fold 1/sqrt(32) into q
#pragma unroll
        for (int r = 0; r < 4; ++r) {
            int slot = b * NB + m0c + w * 16 + quad * 4 + r;
#pragma unroll
            for (int c = 0; c < 4; ++c) {
                int col = n0 + c * 16 + l15;
                qkvh[(size_t)slot * 512 + col] = f2bf((acc[c][r] + bias[col]) * sc);
            }
        }
    } else {
        int n = m0c + w * 16 + quad * 4;
#pragma unroll
        for (int c = 0; c < 4; ++c) {
            int col = n0 + c * 16 + l15 - 512;
            int hidx = col >> 5, d = col & 31;
            float bs = bias[n0 + c * 16 + l15];
            ushort4 u;
            u.x = f2bf(acc[c][0] + bs);
            u.y = f2bf(acc[c][1] + bs);
            u.z = f2bf(acc[c][2] + bs);
            u.w = f2bf(acc[c][3] + bs);
            *(ushort4*)&vT[(size_t)((b * HEADS + hidx) * 32 + d) * NB + n] = u;
        }
    }
}

// ---------------- MFMA attention: fully compact (q AND k), S^T + b64 P + R6 PV -------
__global__ __launch_bounds__(256) void attn_mfma(
    const unsigned short* __restrict__ qkvh,
    const unsigned short* __restrict__ vT,
    const unsigned char* __restrict__ emaskP,
    const float* __restrict__ table,
    const int* __restrict__ nv,
    unsigned short* __restrict__ OpH, float* __restrict__ lpart)
{
    __shared__ unsigned short P[4][16][72];
    __shared__ float tab2m[16];

    int t = threadIdx.x;
    int w = t >> 6, l = t & 63;
    int l15 = l & 15, quad = l >> 4;
    int h = blockIdx.x;
    int qt = blockIdx.y;
    int z = blockIdx.z, b = z >> 2, sp = z & 3;

    if (t < 16) tab2m[t] = (t >= 1 && t < 10) ? __expf(table[(t - 1) * 8 + h]) : 0.f;
    __syncthreads();

    int nvb = nv[b];
    int qt16 = qt * 4 + w;
    int q0c = qt16 * 16;
    if (q0c >= nvb) return;

    int nkt = (nvb + 63) >> 6;
    int tps = (nkt + 3) >> 2;
    int kbase = sp * tps * 64;
    int kend = min(kbase + tps * 64, nkt * 64);

    bf16x8 bq = *(const bf16x8*)(qkvh + (size_t)(b * NB + q0c + l15) * 512 + h * 32 + quad * 8);

    const unsigned short* kp = qkvh + (size_t)(b * NB + l15) * 512 + 256 + h * 32 + quad * 8;
    const unsigned short* vp = vT + (size_t)((b * HEADS + h) * 32 + l15) * NB + quad * 8;
    const unsigned char* ep = emaskP + (size_t)((b * 128 + qt16) * 32) * 512 + l * 8;

    float lacc = 0.f;
    f32x4 O0 = {0.f, 0.f, 0.f, 0.f}, O1 = {0.f, 0.f, 0.f, 0.f};

    bf16x8 kA[4], kB[4];
    bf16x8 vA[2][2], vB[2][2];
    int2 eA, eB;

    auto loadtile = [&](bf16x8 (&kf)[4], bf16x8 (&vf)[2][2], int2& ef, int m0) {
#pragma unroll
        for (int t16 = 0; t16 < 4; ++t16)
            kf[t16] = *(const bf16x8*)(kp + (size_t)(m0 + t16 * 16) * 512);
#pragma unroll
        for (int ks = 0; ks < 2; ++ks) {
            vf[ks][0] = *(const bf16x8*)(vp + m0 + ks * 32);
            vf[ks][1] = *(const bf16x8*)(vp + 16 * NB + m0 + ks * 32);
        }
        ef = *(const int2*)(ep + (size_t)(m0 >> 6) * 512);
    };

    auto process = [&](const bf16x8 (&kf)[4], const bf16x8 (&vf)[2][2], const int2& ef) {
#pragma unroll
        for (int t16 = 0; t16 < 4; ++t16) {
            f32x4 zero = {0.f, 0.f, 0.f, 0.f};
            f32x4 sT = __builtin_amdgcn_mfma_f32_16x16x32_bf16(kf[t16], bq, zero, 0, 0, 0);
            unsigned int e = ((unsigned int)((t16 < 2) ? ef.x : ef.y)) >> ((t16 & 1) * 16);
            float p0 = __expf(sT[0]) * tab2m[e & 0xFu];
            float p1 = __expf(sT[1]) * tab2m[(e >> 4) & 0xFu];
            float p2 = __expf(sT[2]) * tab2m[(e >> 8) & 0xFu];
            float p3 = __expf(sT[3]) * tab2m[(e >> 12) & 0xFu];
            lacc += (p0 + p1) + (p2 + p3);
            bf16x4 pb;
            pb[0] = (short)f2bf(p0); pb[1] = (short)f2bf(p1);
            pb[2] = (short)f2bf(p2); pb[3] = (short)f2bf(p3);
            *(bf16x4*)&P[w][l15][t16 * 16 + quad * 4] = pb;
        }
#pragma unroll
        for (int ks = 0; ks < 2; ++ks) {
            bf16x8 pa = *(const bf16x8*)&P[w][l15][ks * 32 + quad * 8];
            O0 = __builtin_amdgcn_mfma_f32_16x16x32_bf16(pa, vf[ks][0], O0, 0, 0, 0);
            O1 = __builtin_amdgcn_mfma_f32_16x16x32_bf16(pa, vf[ks][1], O1, 0, 0, 0);
        }
    };

    if (kbase < kend) {
        loadtile(kA, vA, eA, kbase);
        for (int m0 = kbase; m0 < kend; m0 += 128) {
            int n1 = (m0 + 64 < kend) ? m0 + 64 : kbase;
            loadtile(kB, vB, eB, n1);
            process(kA, vA, eA);
            if (m0 + 128 < kend) loadtile(kA, vA, eA, m0 + 128);
            if (m0 + 64 < kend) process(kB, vB, eB);
        }
    }

    lacc += __shfl_xor(lacc, 16);
    lacc += __shfl_xor(lacc, 32);

    unsigned short* Ob = OpH + (size_t)sp * ROWS * DIMM;
#pragma unroll
    for (int r = 0; r < 4; ++r) {
        int slot = q0c + quad * 4 + r;
        if (slot < nvb) {
            Ob[(size_t)(b * NB + slot) * DIMM + h * 32 + l15]      = f2bf(O0[r]);
            Ob[(size_t)(b * NB + slot) * DIMM + h * 32 + 16 + l15] = f2bf(O1[r]);
        }
    }
    if (quad == 0 && q0c + l15 < nvb)
        lpart[(size_t)sp * ROWS * 8 + (size_t)(b * NB + q0c + l15) * 8 + h] = lacc;
}

// ---------------- megaback: 16-row compute (0..255) + masked copy (256..) ------------
// Cross-barrier weight prefetch: initial proj/f1T/f2T register loads issued before the
// preceding __syncthreads (pure global reads, no LDS dependence) to hide phase-start
// latency. Compute structure otherwise identical to R13/R15-proven version.
__global__ __launch_bounds__(1024) void megaback(
    const unsigned short* __restrict__ OpH, const float* __restrict__ lpart,
    const unsigned short* __restrict__ projT, const float* __restrict__ proj_b,
    const float* __restrict__ x, const void* __restrict__ nmask,
    const float* __restrict__ g2, const float* __restrict__ b2,
    const unsigned short* __restrict__ f1T, const float* __restrict__ ffn_b1,
    const unsigned short* __restrict__ f2T, const float* __restrict__ ffn_b2,
    const int* __restrict__ nv, const unsigned short* __restrict__ qidx,
    float* __restrict__ out)
{
    __shared__ float rinv_l[16][8];
    __shared__ float stats[16][2];
    __shared__ float redn[16][16][2];
    __shared__ unsigned short Astage[16][264];
    __shared__ float x1s[16][260];
    __shared__ unsigned short hstage[16][264];
    __shared__ unsigned short midstage[16][1032];
    __shared__ int fsh;

    int t = threadIdx.x;
    int bid = blockIdx.x;

    if (bid >= 256) {
        // masked-row copy: out[row] = x[row] (proj*0, ffn*0 => exact)
        if (t == 0) fsh = 0;
        __syncthreads();
        if (((const unsigned char*)nmask)[4 * t + 1] != 0) fsh = 1;
        __syncthreads();
        int fm = fsh;
        int row = (bid - 256) * 32 + (t >> 5);
        if (!get_mask(nmask, fm, row)) {
            int c0 = (t & 31) * 8;
            float4 v0 = *(const float4*)&x[(size_t)row * DIMM + c0];
            float4 v1 = *(const float4*)&x[(size_t)row * DIMM + c0 + 4];
            *(float4*)&out[(size_t)row * DIMM + c0]     = v0;
            *(float4*)&out[(size_t)row * DIMM + c0 + 4] = v1;
        }
        return;
    }

    int w = t >> 6, l = t & 63;
    int l15 = l & 15, quad = l >> 4;
    int b = bid >> 7;
    int s0 = (bid & 127) * 16;
    int nvb = nv[b];
    if (s0 >= nvb) return;                    // block-uniform, before barriers
    int slot0 = b * NB + s0;
    int col = w * 16 + l15;

    // --- prefetch proj weights (in flight during rinv + combine phases) ---
    const unsigned short* bpp = projT + (size_t)col * 256 + quad * 8;
    bf16x8 psb[4];
#pragma unroll
    for (int i = 0; i < 4; ++i) psb[i] = *(const bf16x8*)(bpp + i * 32);

    if (t < 128) {
        int row = t >> 3, h = t & 7;
        float s = 0.f;
#pragma unroll
        for (int sp = 0; sp < 4; ++sp)
            s += lpart[(size_t)sp * ROWS * 8 + (size_t)(slot0 + row) * 8 + h];
        rinv_l[row][h] = (s > 0.f) ? 1.f / s : 0.f;
    }
    __syncthreads();

    {
        int row = t >> 6, col4 = (t & 63) * 4;
        float rinv = rinv_l[row][col4 >> 5];
        float o0 = 0.f, o1 = 0.f, o2 = 0.f, o3 = 0.f;
#pragma unroll
        for (int sp = 0; sp < 4; ++sp) {
            ushort4 u = *(const ushort4*)&OpH[(size_t)sp * ROWS * DIMM +
                                             (size_t)(slot0 + row) * DIMM + col4];
            o0 += bf2f(u.x); o1 += bf2f(u.y); o2 += bf2f(u.z); o3 += bf2f(u.w);
        }
        ushort4 u;
        u.x = f2bf(o0 * rinv); u.y = f2bf(o1 * rinv);
        u.z = f2bf(o2 * rinv); u.w = f2bf(o3 * rinv);
        *(ushort4*)&Astage[row][col4] = u;
    }
    __syncthreads();

    {
        f32x4 acc = (f32x4){0.f, 0.f, 0.f, 0.f};
#pragma unroll
        for (int ch = 0; ch < 8; ++ch) {
            bf16x8 a = *(const bf16x8*)&Astage[l15][ch * 32 + quad * 8];
            acc = __builtin_amdgcn_mfma_f32_16x16x32_bf16(a, psb[ch & 3], acc, 0, 0, 0);
            if (ch + 4 < 8) psb[ch & 3] = *(const bf16x8*)(bpp + (ch + 4) * 32);
        }
        float bs = proj_b[col];
#pragma unroll
        for (int r = 0; r < 4; ++r) {
            int row = quad * 4 + r;
            int grow = b * NB + qidx[(size_t)(slot0 + row)];
            float v = (acc[r] + bs) + x[(size_t)grow * DIMM + col];   // mask==1 here
            x1s[row][col] = v;
            float s = v, s2 = v * v;
#pragma unroll
            for (int off = 1; off < 16; off <<= 1) {
                s += __shfl_xor(s, off); s2 += __shfl_xor(s2, off);
            }
            if (l15 == 0) { redn[row][w][0] = s; redn[row][w][1] = s2; }
        }
    }
    // --- prefetch ffn1 initial weights (in flight during stats + LN2 phases) ---
    const unsigned short* bpf1 = f1T + (size_t)(w * 64 + l15) * 256 + quad * 8;
    bf16x8 f1A[4];
#pragma unroll
    for (int c = 0; c < 4; ++c) f1A[c] = *(const bf16x8*)(bpf1 + (size_t)(c * 16) * 256);
    __syncthreads();
    if (t < 16) {
        float s = 0.f, s2 = 0.f;
#pragma unroll
        for (int ww = 0; ww < 16; ++ww) { s += redn[t][ww][0]; s2 += redn[t][ww][1]; }
        float mean = s * (1.f / DIMM);
        float var  = s2 * (1.f / DIMM) - mean * mean;
        stats[t][0] = mean; stats[t][1] = rsqrtf(var + 1e-5f);
    }
    __syncthreads();

    {
        float gv = g2[col], bv = b2[col];
#pragma unroll
        for (int r = 0; r < 4; ++r) {
            int row = quad * 4 + r;
            float hv = (x1s[row][col] - stats[row][0]) * stats[row][1] * gv + bv;
            hstage[row][col] = f2bf(hv);
        }
    }
    __syncthreads();

    {
        f32x4 acc[4];
#pragma unroll
        for (int c = 0; c < 4; ++c) acc[c] = (f32x4){0.f, 0.f, 0.f, 0.f};
        bf16x8 bB[4];
#pragma unroll
        for (int ch = 0; ch < 8; ++ch) {
            bf16x8 a = *(const bf16x8*)&hstage[l15][ch * 32 + quad * 8];
            if (ch + 1 < 8) {
#pragma unroll
                for (int c = 0; c < 4; ++c)
                    bB[c] = *(const bf16x8*)(bpf1 + (size_t)(c * 16) * 256 + (ch + 1) * 32);
            }
#pragma unroll
            for (int c = 0; c < 4; ++c)
                acc[c] = __builtin_amdgcn_mfma_f32_16x16x32_bf16(a, f1A[c], acc[c], 0, 0, 0);
#pragma unroll
            for (int c = 0; c < 4; ++c) f1A[c] = bB[c];
        }
#pragma unroll
        for (int c = 0; c < 4; ++c) {
            int colf = w * 64 + c * 16 + l15;
            float bs = ffn_b1[colf];
#pragma unroll
            for (int r = 0; r < 4; ++r) {
                float v = acc[c][r] + bs;
                float x2 = v * v;
                float p = v * fmaf(0.07135481f, x2, 1.5957691f);
                float e = __expf(p);
                float gl = v * (e / (e + 1.f));
                midstage[quad * 4 + r][colf] = f2bf(gl);
            }
        }
    }
    // --- prefetch ffn2 initial weights (in flight across the barrier) ---
    const unsigned short* bpf2 = f2T + (size_t)col * 1024 + quad * 8;
    bf16x8 f2sb[4];
#pragma unroll
    for (int i = 0; i < 4; ++i) f2sb[i] = *(const bf16x8*)(bpf2 + i * 32);
    __syncthreads();

    {
        f32x4 acc = (f32x4){0.f, 0.f, 0.f, 0.f};
#pragma unroll
        for (int ch = 0; ch < 32; ++ch) {
            bf16x8 a = *(const bf16x8*)&midstage[l15][ch * 32 + quad * 8];
            acc = __builtin_amdgcn_mfma_f32_16x16x32_bf16(a, f2sb[ch & 3], acc, 0, 0, 0);
            if (ch + 4 < 32) f2sb[ch & 3] = *(const bf16x8*)(bpf2 + (ch + 4) * 32);
        }
        float bs = ffn_b2[col];
#pragma unroll
        for (int r = 0; r < 4; ++r) {
            int row = quad * 4 + r;
            if (s0 + row < nvb) {
                int grow = b * NB + qidx[(size_t)(slot0 + row)];
                out[(size_t)grow * DIMM + col] = x1s[row][col] + (acc[r] + bs);
            }
        }
    }
}

// ---------------- launch ----------------
extern "C" void kernel_launch(void* const* d_in, const int* in_sizes, int n_in,
                              void* d_out, int out_size, void* d_ws, size_t ws_size,
                              hipStream_t stream) {
    const float* x       = (const float*)d_in[0];
    const int*   etypes  = (const int*)d_in[1];
    const void*  nmask   = d_in[2];
    const float* qkv_w   = (const float*)d_in[3];
    const float* qkv_b   = (const float*)d_in[4];
    const float* proj_w  = (const float*)d_in[5];
    const float* proj_b  = (const float*)d_in[6];
    const float* table   = (const float*)d_in[7];
    const float* ln1_g   = (const float*)d_in[8];
    const float* ln1_b   = (const float*)d_in[9];
    const float* ln2_g   = (const float*)d_in[10];
    const float* ln2_b   = (const float*)d_in[11];
    const float* ffn_w1  = (const float*)d_in[12];
    const float* ffn_b1  = (const float*)d_in[13];
    const float* ffn_w2  = (const float*)d_in[14];
    const float* ffn_b2  = (const float*)d_in[15];
    float* out = (float*)d_out;
    float* ws  = (float*)d_ws;

    float* lpart = ws;                               // 131,072 f (512 KB)
    unsigned short* ub = (unsigned short*)(ws + 131072);
    unsigned short* h_ln   = ub;                     // 1,048,576 us (compact)
    unsigned short* qkvh   = ub + 1048576;           // 2,097,152 (compact)
    unsigned short* vT     = ub + 3145728;           // 1,048,576 (compact)
    unsigned short* OpH    = ub + 4194304;           // 4,194,304 (compact, 4 splits)
    unsigned short* qkvT   = ub + 8388608;           // 196,608
    unsigned short* projT  = ub + 8585216;           // 65,536
    unsigned short* f1T    = ub + 8650752;           // 262,144
    unsigned short* f2T    = ub + 8912896;           // 262,144
    unsigned char* emaskP  = (unsigned char*)(ub + 9175040);  // 4,194,304 B
    unsigned short* qidx   = ub + 11272192;          // 4,096 us
    int* nv                = (int*)(ub + 11276288);  // 2 ints

    scan_w2bft_kernel<<<dim3(BB + 192), dim3(256), 0, stream>>>(
        nmask, nv, qidx, qkv_w, proj_w, ffn_w1, ffn_w2, qkvT, projT, f1T, f2T);
    prep_kernel<<<dim3(2560), dim3(256), 0, stream>>>(
        x, ln1_g, ln1_b, h_ln, etypes, emaskP, nv, qidx);
    gemm_qkv_mfma<<<dim3(12, 32, BB), dim3(256), 0, stream>>>(h_ln, qkvT, qkv_b, nv, qkvh, vT);
    attn_mfma<<<dim3(HEADS, NB/64, BB*4), dim3(256), 0, stream>>>(
        qkvh, vT, emaskP, table, nv, OpH, lpart);
    megaback<<<dim3(256 + ROWS/32), dim3(1024), 0, stream>>>(
        OpH, lpart, projT, proj_b, x, nmask, ln2_g, ln2_b,
        f1T, ffn_b1, f2T, ffn_b2, nv, qidx, out);
}

// Round 17
// 191.646 us; speedup vs baseline: 1.2063x; 1.0100x over previous
//
#include <hip/hip_runtime.h>
#include <math.h>

#define DIMM 256
#define HEADS 8
#define NB 2048
#define BB 2
#define ROWS (BB*NB)   // 4096

typedef __attribute__((ext_vector_type(8))) short bf16x8;
typedef __attribute__((ext_vector_type(4))) short bf16x4;
typedef __attribute__((ext_vector_type(4))) float f32x4;

__device__ inline unsigned short f2bf(float f) {
    unsigned int u = __float_as_uint(f);
    u += 0x7FFFu + ((u >> 16) & 1u);           // RNE
    return (unsigned short)(u >> 16);
}
__device__ inline float bf2f(unsigned short u) {
    return __uint_as_float(((unsigned int)u) << 16);
}

__device__ inline int get_mask(const void* nm, int fmt, int idx) {
    if (fmt) return ((const unsigned char*)nm)[idx] != 0;
    return ((const int*)nm)[idx] != 0;
}

// ---------------- scan (blocks 0..BB-1, parallel prefix) + w2bfT (BB..BB+191) --------
__global__ __launch_bounds__(256) void scan_w2bft_kernel(
    const void* __restrict__ nmask, int* __restrict__ nv,
    unsigned short* __restrict__ qidx,
    const float* __restrict__ w0, const float* __restrict__ w1,
    const float* __restrict__ w2, const float* __restrict__ w3,
    unsigned short* __restrict__ o0, unsigned short* __restrict__ o1,
    unsigned short* __restrict__ o2, unsigned short* __restrict__ o3)
{
    __shared__ float tile[64][65];
    __shared__ int fsh;
    __shared__ int cnt[256];
    int bid = blockIdx.x, t = threadIdx.x;
    if (bid < BB) {
        if (t == 0) fsh = 0;
        __syncthreads();
        if (((const unsigned char*)nmask)[4 * t + 1] != 0) fsh = 1;
        __syncthreads();
        int fm = fsh;
        int b = bid;
        int m[8]; int c = 0;
#pragma unroll
        for (int i = 0; i < 8; ++i) {
            m[i] = get_mask(nmask, fm, b * NB + t * 8 + i);
            c += m[i];
        }
        cnt[t] = c;
        __syncthreads();
        // Hillis-Steele inclusive scan over 256 entries
#pragma unroll
        for (int off = 1; off < 256; off <<= 1) {
            int v = (t >= off) ? cnt[t - off] : 0;
            __syncthreads();
            cnt[t] += v;
            __syncthreads();
        }
        int mybase = cnt[t] - c;
        if (t == 255) nv[b] = cnt[255];
        int off = mybase;
#pragma unroll
        for (int i = 0; i < 8; ++i) {
            int row = t * 8 + i;
            if (m[i]) qidx[b * NB + off++] = (unsigned short)row;
        }
        __syncthreads();
        if (t == 0) {   // pad to multiple of 64 with last valid row (safe dup reads)
            int n = cnt[255];
            unsigned short last = (n > 0) ? qidx[b * NB + n - 1] : (unsigned short)0;
            int padend = (n + 63) & ~63;
            for (int i = n; i < padend; ++i) qidx[b * NB + i] = last;
        }
    } else {
        int wb = bid - BB;
        const float* src; unsigned short* dst; int K, N, idx;
        if (wb < 48)       { src = w0; dst = o0; K = 256;  N = 768;  idx = wb; }
        else if (wb < 64)  { src = w1; dst = o1; K = 256;  N = 256;  idx = wb - 48; }
        else if (wb < 128) { src = w2; dst = o2; K = 256;  N = 1024; idx = wb - 64; }
        else               { src = w3; dst = o3; K = 1024; N = 256;  idx = wb - 128; }
        int ntiles = N >> 6;
        int k0 = (idx / ntiles) * 64, n0 = (idx % ntiles) * 64;
        int r = t >> 4, c4 = (t & 15) * 4;
#pragma unroll
        for (int i = 0; i < 4; ++i) {
            float4 v = *(const float4*)&src[(size_t)(k0 + r + i * 16) * N + n0 + c4];
            tile[r + i * 16][c4 + 0] = v.x;
            tile[r + i * 16][c4 + 1] = v.y;
            tile[r + i * 16][c4 + 2] = v.z;
            tile[r + i * 16][c4 + 3] = v.w;
        }
        __syncthreads();
#pragma unroll
        for (int i = 0; i < 4; ++i) {
            int n = n0 + r + i * 16;
            ushort4 u;
            u.x = f2bf(tile[c4 + 0][r + i * 16]);
            u.y = f2bf(tile[c4 + 1][r + i * 16]);
            u.z = f2bf(tile[c4 + 2][r + i * 16]);
            u.w = f2bf(tile[c4 + 3][r + i * 16]);
            *(ushort4*)&dst[(size_t)n * K + k0 + c4] = u;
        }
    }
}

// ---------------- fused: qkv GEMM w/ inline LN1 (0..767) + emaskP (768..2815) --------
// qkv part: block = (n0 of 12, m0c of 32, b). LN1 for the block's 64 compact rows is
// computed inline into LDS (bf16, stride 264 -> conflict-free b128 A-frag reads),
// then the R16-proven double-buffered MFMA K-loop runs with A from LDS.
// emask part: identical to R16 prep (4-bit fully-compact codes, LDS key staging).
__global__ __launch_bounds__(256) void qkv_emask_kernel(
    const float* __restrict__ x, const float* __restrict__ ln1_g,
    const float* __restrict__ ln1_b,
    const unsigned short* __restrict__ Bt, const float* __restrict__ bias,
    const int* __restrict__ etypes,
    unsigned char* __restrict__ emaskP,
    const int* __restrict__ nv, const unsigned short* __restrict__ qidx,
    unsigned short* __restrict__ qkvh, unsigned short* __restrict__ vT)
{
    __shared__ unsigned short Ah[64][264];     // inline-LN'd A tile (bf16)
    __shared__ unsigned short kq[4][64];       // emask: per-wave staged key origins
    int bid = blockIdx.x, t = threadIdx.x;
    const int K = 256;

    if (bid < 768) {
        int q = bid;
        int n0i = q % 12; q /= 12;
        int m0i = q % 32;
        int b = q / 32;
        int n0 = n0i * 64;
        int m0c = m0i * 64;
        int nvp = (nv[b] + 63) & ~63;
        if (m0c >= nvp) return;                // block-uniform, before barriers

        // --- inline LN1: 8 passes x 8 rows, 32 lanes per row ---
        for (int p = 0; p < 8; ++p) {
            int lr = p * 8 + (t >> 5);
            int lane32 = t & 31;
            int row = qidx[b * NB + m0c + lr];   // padded to mult-64, safe
            int c0 = lane32 * 8;
            const float* xr = x + (size_t)(b * NB + row) * DIMM;
            float4 v0 = *(const float4*)&xr[c0];
            float4 v1 = *(const float4*)&xr[c0 + 4];
            float s  = v0.x + v0.y + v0.z + v0.w + v1.x + v1.y + v1.z + v1.w;
            float s2 = v0.x*v0.x + v0.y*v0.y + v0.z*v0.z + v0.w*v0.w
                     + v1.x*v1.x + v1.y*v1.y + v1.z*v1.z + v1.w*v1.w;
#pragma unroll
            for (int off = 16; off >= 1; off >>= 1) {
                s  += __shfl_xor(s,  off);
                s2 += __shfl_xor(s2, off);
            }
            float mean = s * (1.0f / DIMM);
            float var  = s2 * (1.0f / DIMM) - mean * mean;
            float rstd = rsqrtf(var + 1e-5f);
            float4 g0 = *(const float4*)&ln1_g[c0], g1 = *(const float4*)&ln1_g[c0 + 4];
            float4 b0 = *(const float4*)&ln1_b[c0], b1 = *(const float4*)&ln1_b[c0 + 4];
            ushort4 u0, u1;
            u0.x = f2bf((v0.x - mean) * rstd * g0.x + b0.x);
            u0.y = f2bf((v0.y - mean) * rstd * g0.y + b0.y);
            u0.z = f2bf((v0.z - mean) * rstd * g0.z + b0.z);
            u0.w = f2bf((v0.w - mean) * rstd * g0.w + b0.w);
            u1.x = f2bf((v1.x - mean) * rstd * g1.x + b1.x);
            u1.y = f2bf((v1.y - mean) * rstd * g1.y + b1.y);
            u1.z = f2bf((v1.z - mean) * rstd * g1.z + b1.z);
            u1.w = f2bf((v1.w - mean) * rstd * g1.w + b1.w);
            *(ushort4*)&Ah[lr][c0]     = u0;
            *(ushort4*)&Ah[lr][c0 + 4] = u1;
        }
        __syncthreads();

        // --- MFMA GEMM: A from LDS, B streamed from global (R16 structure) ---
        int w = t >> 6, l = t & 63;
        int l15 = l & 15, quad = l >> 4;
        const unsigned short* bp = Bt + (size_t)(n0 + l15) * K + quad * 8;
        const unsigned short* alds = &Ah[w * 16 + l15][quad * 8];

        f32x4 acc[4];
#pragma unroll
        for (int c = 0; c < 4; ++c) acc[c] = (f32x4){0.f, 0.f, 0.f, 0.f};

        bf16x8 aA, bA[4], aB, bB[4];
        auto ld = [&](bf16x8& af, bf16x8 (&bf)[4], int k0) {
            af = *(const bf16x8*)(alds + k0);
#pragma unroll
            for (int c = 0; c < 4; ++c)
                bf[c] = *(const bf16x8*)(bp + (size_t)(c * 16) * K + k0);
        };
        auto pr = [&](const bf16x8& af, const bf16x8 (&bf)[4]) {
#pragma unroll
            for (int c = 0; c < 4; ++c)
                acc[c] = __builtin_amdgcn_mfma_f32_16x16x32_bf16(af, bf[c], acc[c], 0, 0, 0);
        };
        ld(aA, bA, 0);
        for (int k0 = 0; k0 < K; k0 += 64) {
            ld(aB, bB, k0 + 32);
            pr(aA, bA);
            if (k0 + 64 < K) ld(aA, bA, k0 + 64);
            pr(aB, bB);
        }

        if (n0 < 512) {
            float sc = (n0 < 256) ? 0.17677669529663689f : 1.0f;   // fold 1/sqrt(32) into q
#pragma unroll
            for (int r = 0; r < 4; ++r) {
                int slot = b * NB + m0c + w * 16 + quad * 4 + r;
#pragma unroll
                for (int c = 0; c < 4; ++c) {
                    int col = n0 + c * 16 + l15;
                    qkvh[(size_t)slot * 512 + col] = f2bf((acc[c][r] + bias[col]) * sc);
                }
            }
        } else {
            int n = m0c + w * 16 + quad * 4;
#pragma unroll
            for (int c = 0; c < 4; ++c) {
                int col = n0 + c * 16 + l15 - 512;
                int hidx = col >> 5, d = col & 31;
                float bs = bias[n0 + c * 16 + l15];
                ushort4 u;
                u.x = f2bf(acc[c][0] + bs);
                u.y = f2bf(acc[c][1] + bs);
                u.z = f2bf(acc[c][2] + bs);
                u.w = f2bf(acc[c][3] + bs);
                *(ushort4*)&vT[(size_t)((b * HEADS + hidx) * 32 + d) * NB + n] = u;
            }
        }
    } else {
        int wu = t >> 6;
        int unit = (bid - 768) * 4 + wu;
        int lane = t & 63, quad = lane >> 4, l15 = lane & 15;
        int b = unit >> 12;
        int qt16 = (unit >> 5) & 127;
        int kt = unit & 31;
        int nvb = nv[b];
        int nvp = (nvb + 63) & ~63;
        if (qt16 * 16 >= nvb || kt * 64 >= nvp) return;
        // stage this unit's 64 key origins: one coalesced lane-load (same-wave LDS)
        kq[wu][lane] = qidx[b * NB + kt * 64 + lane];
        int slot = qt16 * 16 + l15;
        int validq = slot < nvb;
        int qr = qidx[b * NB + slot];
        const int* erow = etypes + (size_t)(b * NB + qr) * NB;
        unsigned int dw[2] = {0u, 0u};
#pragma unroll
        for (int t16 = 0; t16 < 4; ++t16) {
            ushort4 ko = *(const ushort4*)&kq[wu][t16 * 16 + quad * 4];
            unsigned short kos[4] = {ko.x, ko.y, ko.z, ko.w};
#pragma unroll
            for (int r = 0; r < 4; ++r) {
                int ks = kt * 64 + t16 * 16 + quad * 4 + r;
                unsigned int code = 0u;
                if (validq && ks < nvb) {
                    int korig = kos[r];
                    int et = erow[korig];
                    if ((et != 0) || (korig == qr)) code = (unsigned int)(et + 1);
                }
                dw[t16 >> 1] |= code << ((t16 & 1) * 16 + r * 4);
            }
        }
        int2 o = {(int)dw[0], (int)dw[1]};
        *(int2*)(emaskP + (size_t)unit * 512 + lane * 8) = o;
    }
}

// ---------------- MFMA attention: fully compact (q AND k), S^T + b64 P + R6 PV -------
__global__ __launch_bounds__(256) void attn_mfma(
    const unsigned short* __restrict__ qkvh,
    const unsigned short* __restrict__ vT,
    const unsigned char* __restrict__ emaskP,
    const float* __restrict__ table,
    const int* __restrict__ nv,
    unsigned short* __restrict__ OpH, float* __restrict__ lpart)
{
    __shared__ unsigned short P[4][16][72];
    __shared__ float tab2m[16];

    int t = threadIdx.x;
    int w = t >> 6, l = t & 63;
    int l15 = l & 15, quad = l >> 4;
    int h = blockIdx.x;
    int qt = blockIdx.y;
    int z = blockIdx.z, b = z >> 2, sp = z & 3;

    if (t < 16) tab2m[t] = (t >= 1 && t < 10) ? __expf(table[(t - 1) * 8 + h]) : 0.f;
    __syncthreads();

    int nvb = nv[b];
    int qt16 = qt * 4 + w;
    int q0c = qt16 * 16;
    if (q0c >= nvb) return;

    int nkt = (nvb + 63) >> 6;
    int tps = (nkt + 3) >> 2;
    int kbase = sp * tps * 64;
    int kend = min(kbase + tps * 64, nkt * 64);

    bf16x8 bq = *(const bf16x8*)(qkvh + (size_t)(b * NB + q0c + l15) * 512 + h * 32 + quad * 8);

    const unsigned short* kp = qkvh + (size_t)(b * NB + l15) * 512 + 256 + h * 32 + quad * 8;
    const unsigned short* vp = vT + (size_t)((b * HEADS + h) * 32 + l15) * NB + quad * 8;
    const unsigned char* ep = emaskP + (size_t)((b * 128 + qt16) * 32) * 512 + l * 8;

    float lacc = 0.f;
    f32x4 O0 = {0.f, 0.f, 0.f, 0.f}, O1 = {0.f, 0.f, 0.f, 0.f};

    bf16x8 kA[4], kB[4];
    bf16x8 vA[2][2], vB[2][2];
    int2 eA, eB;

    auto loadtile = [&](bf16x8 (&kf)[4], bf16x8 (&vf)[2][2], int2& ef, int m0) {
#pragma unroll
        for (int t16 = 0; t16 < 4; ++t16)
            kf[t16] = *(const bf16x8*)(kp + (size_t)(m0 + t16 * 16) * 512);
#pragma unroll
        for (int ks = 0; ks < 2; ++ks) {
            vf[ks][0] = *(const bf16x8*)(vp + m0 + ks * 32);
            vf[ks][1] = *(const bf16x8*)(vp + 16 * NB + m0 + ks * 32);
        }
        ef = *(const int2*)(ep + (size_t)(m0 >> 6) * 512);
    };

    auto process = [&](const bf16x8 (&kf)[4], const bf16x8 (&vf)[2][2], const int2& ef) {
#pragma unroll
        for (int t16 = 0; t16 < 4; ++t16) {
            f32x4 zero = {0.f, 0.f, 0.f, 0.f};
            f32x4 sT = __builtin_amdgcn_mfma_f32_16x16x32_bf16(kf[t16], bq, zero, 0, 0, 0);
            unsigned int e = ((unsigned int)((t16 < 2) ? ef.x : ef.y)) >> ((t16 & 1) * 16);
            float p0 = __expf(sT[0]) * tab2m[e & 0xFu];
            float p1 = __expf(sT[1]) * tab2m[(e >> 4) & 0xFu];
            float p2 = __expf(sT[2]) * tab2m[(e >> 8) & 0xFu];
            float p3 = __expf(sT[3]) * tab2m[(e >> 12) & 0xFu];
            lacc += (p0 + p1) + (p2 + p3);
            bf16x4 pb;
            pb[0] = (short)f2bf(p0); pb[1] = (short)f2bf(p1);
            pb[2] = (short)f2bf(p2); pb[3] = (short)f2bf(p3);
            *(bf16x4*)&P[w][l15][t16 * 16 + quad * 4] = pb;
        }
#pragma unroll
        for (int ks = 0; ks < 2; ++ks) {
            bf16x8 pa = *(const bf16x8*)&P[w][l15][ks * 32 + quad * 8];
            O0 = __builtin_amdgcn_mfma_f32_16x16x32_bf16(pa, vf[ks][0], O0, 0, 0, 0);
            O1 = __builtin_amdgcn_mfma_f32_16x16x32_bf16(pa, vf[ks][1], O1, 0, 0, 0);
        }
    };

    if (kbase < kend) {
        loadtile(kA, vA, eA, kbase);
        for (int m0 = kbase; m0 < kend; m0 += 128) {
            int n1 = (m0 + 64 < kend) ? m0 + 64 : kbase;
            loadtile(kB, vB, eB, n1);
            process(kA, vA, eA);
            if (m0 + 128 < kend) loadtile(kA, vA, eA, m0 + 128);
            if (m0 + 64 < kend) process(kB, vB, eB);
        }
    }

    lacc += __shfl_xor(lacc, 16);
    lacc += __shfl_xor(lacc, 32);

    unsigned short* Ob = OpH + (size_t)sp * ROWS * DIMM;
#pragma unroll
    for (int r = 0; r < 4; ++r) {
        int slot = q0c + quad * 4 + r;
        if (slot < nvb) {
            Ob[(size_t)(b * NB + slot) * DIMM + h * 32 + l15]      = f2bf(O0[r]);
            Ob[(size_t)(b * NB + slot) * DIMM + h * 32 + 16 + l15] = f2bf(O1[r]);
        }
    }
    if (quad == 0 && q0c + l15 < nvb)
        lpart[(size_t)sp * ROWS * 8 + (size_t)(b * NB + q0c + l15) * 8 + h] = lacc;
}

// ---------------- megaback: 16-row compute (0..255) + masked copy (256..) ------------
__global__ __launch_bounds__(1024) void megaback(
    const unsigned short* __restrict__ OpH, const float* __restrict__ lpart,
    const unsigned short* __restrict__ projT, const float* __restrict__ proj_b,
    const float* __restrict__ x, const void* __restrict__ nmask,
    const float* __restrict__ g2, const float* __restrict__ b2,
    const unsigned short* __restrict__ f1T, const float* __restrict__ ffn_b1,
    const unsigned short* __restrict__ f2T, const float* __restrict__ ffn_b2,
    const int* __restrict__ nv, const unsigned short* __restrict__ qidx,
    float* __restrict__ out)
{
    __shared__ float rinv_l[16][8];
    __shared__ float stats[16][2];
    __shared__ float redn[16][16][2];
    __shared__ unsigned short Astage[16][264];
    __shared__ float x1s[16][260];
    __shared__ unsigned short hstage[16][264];
    __shared__ unsigned short midstage[16][1032];
    __shared__ int fsh;

    int t = threadIdx.x;
    int bid = blockIdx.x;

    if (bid >= 256) {
        // masked-row copy: out[row] = x[row] (proj*0, ffn*0 => exact)
        if (t == 0) fsh = 0;
        __syncthreads();
        if (((const unsigned char*)nmask)[4 * t + 1] != 0) fsh = 1;
        __syncthreads();
        int fm = fsh;
        int row = (bid - 256) * 32 + (t >> 5);
        if (!get_mask(nmask, fm, row)) {
            int c0 = (t & 31) * 8;
            float4 v0 = *(const float4*)&x[(size_t)row * DIMM + c0];
            float4 v1 = *(const float4*)&x[(size_t)row * DIMM + c0 + 4];
            *(float4*)&out[(size_t)row * DIMM + c0]     = v0;
            *(float4*)&out[(size_t)row * DIMM + c0 + 4] = v1;
        }
        return;
    }

    int w = t >> 6, l = t & 63;
    int l15 = l & 15, quad = l >> 4;
    int b = bid >> 7;
    int s0 = (bid & 127) * 16;
    int nvb = nv[b];
    if (s0 >= nvb) return;                    // block-uniform, before barriers
    int slot0 = b * NB + s0;
    int col = w * 16 + l15;

    // --- prefetch proj weights (in flight during rinv + combine phases) ---
    const unsigned short* bpp = projT + (size_t)col * 256 + quad * 8;
    bf16x8 psb[4];
#pragma unroll
    for (int i = 0; i < 4; ++i) psb[i] = *(const bf16x8*)(bpp + i * 32);

    if (t < 128) {
        int row = t >> 3, h = t & 7;
        float s = 0.f;
#pragma unroll
        for (int sp = 0; sp < 4; ++sp)
            s += lpart[(size_t)sp * ROWS * 8 + (size_t)(slot0 + row) * 8 + h];
        rinv_l[row][h] = (s > 0.f) ? 1.f / s : 0.f;
    }
    __syncthreads();

    {
        int row = t >> 6, col4 = (t & 63) * 4;
        float rinv = rinv_l[row][col4 >> 5];
        float o0 = 0.f, o1 = 0.f, o2 = 0.f, o3 = 0.f;
#pragma unroll
        for (int sp = 0; sp < 4; ++sp) {
            ushort4 u = *(const ushort4*)&OpH[(size_t)sp * ROWS * DIMM +
                                             (size_t)(slot0 + row) * DIMM + col4];
            o0 += bf2f(u.x); o1 += bf2f(u.y); o2 += bf2f(u.z); o3 += bf2f(u.w);
        }
        ushort4 u;
        u.x = f2bf(o0 * rinv); u.y = f2bf(o1 * rinv);
        u.z = f2bf(o2 * rinv); u.w = f2bf(o3 * rinv);
        *(ushort4*)&Astage[row][col4] = u;
    }
    __syncthreads();

    {
        f32x4 acc = (f32x4){0.f, 0.f, 0.f, 0.f};
#pragma unroll
        for (int ch = 0; ch < 8; ++ch) {
            bf16x8 a = *(const bf16x8*)&Astage[l15][ch * 32 + quad * 8];
            acc = __builtin_amdgcn_mfma_f32_16x16x32_bf16(a, psb[ch & 3], acc, 0, 0, 0);
            if (ch + 4 < 8) psb[ch & 3] = *(const bf16x8*)(bpp + (ch + 4) * 32);
        }
        float bs = proj_b[col];
#pragma unroll
        for (int r = 0; r < 4; ++r) {
            int row = quad * 4 + r;
            int grow = b * NB + qidx[(size_t)(slot0 + row)];
            float v = (acc[r] + bs) + x[(size_t)grow * DIMM + col];   // mask==1 here
            x1s[row][col] = v;
            float s = v, s2 = v * v;
#pragma unroll
            for (int off = 1; off < 16; off <<= 1) {
                s += __shfl_xor(s, off); s2 += __shfl_xor(s2, off);
            }
            if (l15 == 0) { redn[row][w][0] = s; redn[row][w][1] = s2; }
        }
    }
    // --- prefetch ffn1 initial weights (in flight during stats + LN2 phases) ---
    const unsigned short* bpf1 = f1T + (size_t)(w * 64 + l15) * 256 + quad * 8;
    bf16x8 f1A[4];
#pragma unroll
    for (int c = 0; c < 4; ++c) f1A[c] = *(const bf16x8*)(bpf1 + (size_t)(c * 16) * 256);
    __syncthreads();
    if (t < 16) {
        float s = 0.f, s2 = 0.f;
#pragma unroll
        for (int ww = 0; ww < 16; ++ww) { s += redn[t][ww][0]; s2 += redn[t][ww][1]; }
        float mean = s * (1.f / DIMM);
        float var  = s2 * (1.f / DIMM) - mean * mean;
        stats[t][0] = mean; stats[t][1] = rsqrtf(var + 1e-5f);
    }
    __syncthreads();

    {
        float gv = g2[col], bv = b2[col];
#pragma unroll
        for (int r = 0; r < 4; ++r) {
            int row = quad * 4 + r;
            float hv = (x1s[row][col] - stats[row][0]) * stats[row][1] * gv + bv;
            hstage[row][col] = f2bf(hv);
        }
    }
    __syncthreads();

    {
        f32x4 acc[4];
#pragma unroll
        for (int c = 0; c < 4; ++c) acc[c] = (f32x4){0.f, 0.f, 0.f, 0.f};
        bf16x8 bB[4];
#pragma unroll
        for (int ch = 0; ch < 8; ++ch) {
            bf16x8 a = *(const bf16x8*)&hstage[l15][ch * 32 + quad * 8];
            if (ch + 1 < 8) {
#pragma unroll
                for (int c = 0; c < 4; ++c)
                    bB[c] = *(const bf16x8*)(bpf1 + (size_t)(c * 16) * 256 + (ch + 1) * 32);
            }
#pragma unroll
            for (int c = 0; c < 4; ++c)
                acc[c] = __builtin_amdgcn_mfma_f32_16x16x32_bf16(a, f1A[c], acc[c], 0, 0, 0);
#pragma unroll
            for (int c = 0; c < 4; ++c) f1A[c] = bB[c];
        }
#pragma unroll
        for (int c = 0; c < 4; ++c) {
            int colf = w * 64 + c * 16 + l15;
            float bs = ffn_b1[colf];
#pragma unroll
            for (int r = 0; r < 4; ++r) {
                float v = acc[c][r] + bs;
                float x2 = v * v;
                float p = v * fmaf(0.07135481f, x2, 1.5957691f);
                float e = __expf(p);
                float gl = v * (e / (e + 1.f));
                midstage[quad * 4 + r][colf] = f2bf(gl);
            }
        }
    }
    // --- prefetch ffn2 initial weights (in flight across the barrier) ---
    const unsigned short* bpf2 = f2T + (size_t)col * 1024 + quad * 8;
    bf16x8 f2sb[4];
#pragma unroll
    for (int i = 0; i < 4; ++i) f2sb[i] = *(const bf16x8*)(bpf2 + i * 32);
    __syncthreads();

    {
        f32x4 acc = (f32x4){0.f, 0.f, 0.f, 0.f};
#pragma unroll
        for (int ch = 0; ch < 32; ++ch) {
            bf16x8 a = *(const bf16x8*)&midstage[l15][ch * 32 + quad * 8];
            acc = __builtin_amdgcn_mfma_f32_16x16x32_bf16(a, f2sb[ch & 3], acc, 0, 0, 0);
            if (ch + 4 < 32) f2sb[ch & 3] = *(const bf16x8*)(bpf2 + (ch + 4) * 32);
        }
        float bs = ffn_b2[col];
#pragma unroll
        for (int r = 0; r < 4; ++r) {
            int row = quad * 4 + r;
            if (s0 + row < nvb) {
                int grow = b * NB + qidx[(size_t)(slot0 + row)];
                out[(size_t)grow * DIMM + col] = x1s[row][col] + (acc[r] + bs);
            }
        }
    }
}

// ---------------- launch ----------------
extern "C" void kernel_launch(void* const* d_in, const int* in_sizes, int n_in,
                              void* d_out, int out_size, void* d_ws, size_t ws_size,
                              hipStream_t stream) {
    const float* x       = (const float*)d_in[0];
    const int*   etypes  = (const int*)d_in[1];
    const void*  nmask   = d_in[2];
    const float* qkv_w   = (const float*)d_in[3];
    const float* qkv_b   = (const float*)d_in[4];
    const float* proj_w  = (const float*)d_in[5];
    const float* proj_b  = (const float*)d_in[6];
    const float* table   = (const float*)d_in[7];
    const float* ln1_g   = (const float*)d_in[8];
    const float* ln1_b   = (const float*)d_in[9];
    const float* ln2_g   = (const float*)d_in[10];
    const float* ln2_b   = (const float*)d_in[11];
    const float* ffn_w1  = (const float*)d_in[12];
    const float* ffn_b1  = (const float*)d_in[13];
    const float* ffn_w2  = (const float*)d_in[14];
    const float* ffn_b2  = (const float*)d_in[15];
    float* out = (float*)d_out;
    float* ws  = (float*)d_ws;

    float* lpart = ws;                               // 131,072 f (512 KB)
    unsigned short* ub = (unsigned short*)(ws + 131072);
    unsigned short* qkvh   = ub + 1048576;           // 2,097,152 (compact)
    unsigned short* vT     = ub + 3145728;           // 1,048,576 (compact)
    unsigned short* OpH    = ub + 4194304;           // 4,194,304 (compact, 4 splits)
    unsigned short* qkvT   = ub + 8388608;           // 196,608
    unsigned short* projT  = ub + 8585216;           // 65,536
    unsigned short* f1T    = ub + 8650752;           // 262,144
    unsigned short* f2T    = ub + 8912896;           // 262,144
    unsigned char* emaskP  = (unsigned char*)(ub + 9175040);  // 4,194,304 B
    unsigned short* qidx   = ub + 11272192;          // 4,096 us
    int* nv                = (int*)(ub + 11276288);  // 2 ints

    scan_w2bft_kernel<<<dim3(BB + 192), dim3(256), 0, stream>>>(
        nmask, nv, qidx, qkv_w, proj_w, ffn_w1, ffn_w2, qkvT, projT, f1T, f2T);
    qkv_emask_kernel<<<dim3(768 + 2048), dim3(256), 0, stream>>>(
        x, ln1_g, ln1_b, qkvT, qkv_b, etypes, emaskP, nv, qidx, qkvh, vT);
    attn_mfma<<<dim3(HEADS, NB/64, BB*4), dim3(256), 0, stream>>>(
        qkvh, vT, emaskP, table, nv, OpH, lpart);
    megaback<<<dim3(256 + ROWS/32), dim3(1024), 0, stream>>>(
        OpH, lpart, projT, proj_b, x, nmask, ln2_g, ln2_b,
        f1T, ffn_b1, f2T, ffn_b2, nv, qidx, out);
}